// Round 2
// baseline (6642.478 us; speedup 1.0000x reference)
//
#include <hip/hip_runtime.h>
#include <hip/hip_bf16.h>
#include <type_traits>

// ---------------------------------------------------------------------------
// LeViT subsample attention (round 1): workspace-slim fp32 pipeline.
//   1. Sx1 = x^T x, cs1 = colsum(x)   (split-K partials, no atomics)
//   2. Sx2 = x'^T x', cs2 over the ::2,::2 subsampled rows
//   3. bnprep: analytic BN scales a,b per output column of W_qkv / W_q
//   4. GEMM1: KV = BN(x @ W_qkv) -> normalized bf16   (192.7 MB)
//   5. qGEMM: Qn = BN(x' @ W_q)  -> normalized bf16   (9.6 MB)
//   6. flash attention (online softmax) -> O bf16     (38.5 MB)
//   7. out = hard_swish(O) @ W_out -> f32
// Total ws: 254,482,944 B (~242.7 MiB) -- fits a 256 MiB scratch.
// ---------------------------------------------------------------------------

static constexpr int M1 = 25088, N1 = 3840, Kc = 384;
static constexpr int M2 = 6272, Dq = 768, OUTD = 512;
static constexpr int CH1 = 14;   // chunks for x^T x   (25088 = 14*1792, 1792%32==0)
static constexpr int CH2 = 7;    // chunks for x'^T x' (6272 = 7*896, 896%32==0)

// ws layout (bytes, all 16B aligned)
static constexpr size_t OFF_KV   = 0;            // bf16 25088x3840
static constexpr size_t OFF_QN   = 192675840;    // bf16 6272x768
static constexpr size_t OFF_O    = 202309632;    // bf16 6272x3072
static constexpr size_t OFF_PS1  = 240844800;    // f32 14x384x384
static constexpr size_t OFF_PCS1 = 249102336;    // f32 14x384
static constexpr size_t OFF_PS2  = 249123840;    // f32 7x384x384
static constexpr size_t OFF_PCS2 = 253252608;    // f32 7x384
static constexpr size_t OFF_SX1  = 253263360;    // f32 384x384
static constexpr size_t OFF_CS1  = 253853184;    // f32 384
static constexpr size_t OFF_SX2  = 253854720;    // f32 384x384
static constexpr size_t OFF_CS2  = 254444544;    // f32 384
static constexpr size_t OFF_A1   = 254446080;    // f32 3840
static constexpr size_t OFF_B1   = 254461440;    // f32 3840
static constexpr size_t OFF_A2   = 254476800;    // f32 768
static constexpr size_t OFF_B2   = 254479872;    // f32 768
static constexpr size_t WS_TOTAL = 254482944;

__device__ __forceinline__ float hswish(float x) {
  float t = fminf(fmaxf(x + 3.0f, 0.0f), 6.0f);
  return x * t * (1.0f / 6.0f);
}

__device__ __forceinline__ void fma4x4(float (&c)[4][4], const float4 a, const float4 b) {
  c[0][0] += a.x*b.x; c[0][1] += a.x*b.y; c[0][2] += a.x*b.z; c[0][3] += a.x*b.w;
  c[1][0] += a.y*b.x; c[1][1] += a.y*b.y; c[1][2] += a.y*b.z; c[1][3] += a.y*b.w;
  c[2][0] += a.z*b.x; c[2][1] += a.z*b.y; c[2][2] += a.z*b.z; c[2][3] += a.z*b.w;
  c[3][0] += a.w*b.x; c[3][1] += a.w*b.y; c[3][2] += a.w*b.z; c[3][3] += a.w*b.w;
}

// ---------------------------------------------------------------------------
// Partial X^T X (64x64 tile per block) + partial colsum (ti==0 blocks).
// GATHER=1: rows come from the ::2,::2 subsample of x.
// grid = (36 tiles, nchunks), block = 256.
// ---------------------------------------------------------------------------
template<int GATHER>
__global__ __launch_bounds__(256) void xtx_partial(
    const float* __restrict__ X, float* __restrict__ pS, float* __restrict__ pcs,
    int rows_per_chunk) {
  const int ti = blockIdx.x / 6, tj = blockIdx.x % 6;
  const int chunk = blockIdx.y;
  const int tid = threadIdx.x;
  const int tx = tid & 15, ty = tid >> 4;
  __shared__ __align__(16) float xa[32][64];
  __shared__ __align__(16) float xb[32][64];
  __shared__ float redcs[256];
  float acc[4][4] = {};
  float cs = 0.f;
  const int cq = tid & 63, rq = tid >> 6;

  for (int rr = 0; rr < rows_per_chunk; rr += 32) {
    #pragma unroll
    for (int l = 0; l < 2; ++l) {
      int f = tid + l * 256;        // 0..511
      int r = f >> 4, c4 = f & 15;  // r 0..31
      int m = chunk * rows_per_chunk + rr + r;
      long grow;
      if constexpr (GATHER) {
        int bb = m / 196, t = m - bb * 196;
        int h2 = t / 14, w2 = t - h2 * 14;
        grow = (long)(bb * 784 + h2 * 56 + w2 * 2);
      } else {
        grow = m;
      }
      const float* src = X + grow * 384;
      *(float4*)&xa[r][c4 * 4] = *(const float4*)(src + ti * 64 + c4 * 4);
      *(float4*)&xb[r][c4 * 4] = *(const float4*)(src + tj * 64 + c4 * 4);
    }
    __syncthreads();
    if (ti == 0) {
      #pragma unroll
      for (int r = 0; r < 8; ++r) cs += xb[rq * 8 + r][cq];
    }
    #pragma unroll
    for (int r = 0; r < 32; ++r) {
      float4 av = *(const float4*)&xa[r][ty * 4];
      float4 bv = *(const float4*)&xb[r][tx * 4];
      fma4x4(acc, av, bv);
    }
    __syncthreads();
  }
  #pragma unroll
  for (int r = 0; r < 4; ++r) {
    *(float4*)(pS + ((long)chunk * 384 + ti * 64 + ty * 4 + r) * 384 + tj * 64 + tx * 4) =
        make_float4(acc[r][0], acc[r][1], acc[r][2], acc[r][3]);
  }
  if (ti == 0) {
    redcs[tid] = cs;
    __syncthreads();
    if (tid < 64) {
      pcs[(long)chunk * 384 + tj * 64 + tid] =
          redcs[tid] + redcs[tid + 64] + redcs[tid + 128] + redcs[tid + 192];
    }
  }
}

__global__ __launch_bounds__(256) void reduce_chunks(
    const float* __restrict__ src, float* __restrict__ dst, int nelem, int nchunks) {
  int i = blockIdx.x * 256 + threadIdx.x;
  if (i >= nelem) return;
  float s = 0.f;
  for (int c = 0; c < nchunks; ++c) s += src[(long)c * nelem + i];
  dst[i] = s;
}

// ---------------------------------------------------------------------------
// Analytic BN prep: per column j of W[384,N]:
//   mean = (cs . w_j)/M ; Ey2 = (w_j^T Sx w_j)/M ; a = rsqrt(var+eps)*scale ;
//   b = -mean*a.   One block per column.
// ---------------------------------------------------------------------------
__global__ __launch_bounds__(256) void bnprep(
    const float* __restrict__ W, const float* __restrict__ Sx, const float* __restrict__ cs,
    const float* __restrict__ scale, float* __restrict__ a, float* __restrict__ b,
    int N, float invM) {
  const int j = blockIdx.x;
  __shared__ __align__(16) float wj[384];
  __shared__ float red[256], red2[256];
  for (int k = threadIdx.x; k < 384; k += 256) wj[k] = W[(long)k * N + j];
  __syncthreads();
  float yy = 0.f, mu = 0.f;
  for (int k = threadIdx.x; k < 384; k += 256) {
    float rowdot = 0.f;
    const float* srow = Sx + (long)k * 384;
    #pragma unroll 8
    for (int l = 0; l < 384; l += 4) {
      float4 s = *(const float4*)(srow + l);
      float4 w = *(const float4*)(&wj[l]);
      rowdot += s.x*w.x + s.y*w.y + s.z*w.z + s.w*w.w;
    }
    yy += wj[k] * rowdot;
    mu += cs[k] * wj[k];
  }
  red[threadIdx.x] = yy; red2[threadIdx.x] = mu;
  __syncthreads();
  for (int s = 128; s > 0; s >>= 1) {
    if (threadIdx.x < s) { red[threadIdx.x] += red[threadIdx.x + s]; red2[threadIdx.x] += red2[threadIdx.x + s]; }
    __syncthreads();
  }
  if (threadIdx.x == 0) {
    float mean = red2[0] * invM;
    float var = red[0] * invM - mean * mean;
    float ai = rsqrtf(var + 1e-5f) * scale[j];
    a[j] = ai;
    b[j] = -mean * ai;
  }
}

// ---------------------------------------------------------------------------
// GEMM: C = op(A)[M,K] @ B[K,N].  AT: float or bf16 A elements.
// AMODE: 0 plain, 1 gather ::2,::2 rows of x, 2 hard_swish(A)
// EPI:   0 f32 store, 1 bf16 store of a[col]*acc + b[col]  (fused BN)
// block 256 = 16x16, 4x4 micro per 64-wide sub-tile. Grids divide exactly.
// ---------------------------------------------------------------------------
template<typename AT, int BM, int BN, int AMODE, int EPI>
__global__ __launch_bounds__(256) void gemm_f32(
    const AT* __restrict__ A, const float* __restrict__ Bm, void* __restrict__ Cout,
    const float* __restrict__ ea, const float* __restrict__ eb, int N, int K) {
  constexpr int RM = BM / 64, RN = BN / 64;
  __shared__ __align__(16) float As[16][BM];
  __shared__ __align__(16) float Bs[16][BN];
  const int tid = threadIdx.x;
  const int n0 = blockIdx.x * BN, m0 = blockIdx.y * BM;
  const int tx = tid & 15, ty = tid >> 4;
  float acc[RM][RN][4][4] = {};

  for (int k0 = 0; k0 < K; k0 += 16) {
    #pragma unroll
    for (int l = 0; l < (BM * 4) / 256; ++l) {
      int f = tid + l * 256;
      int row = f >> 2, kq = f & 3;
      int gm = m0 + row;
      long aoff;
      if constexpr (AMODE == 1) {
        int bb = gm / 196, t = gm - bb * 196;
        int h2 = t / 14, w2 = t - h2 * 14;
        aoff = (long)(bb * 784 + h2 * 56 + w2 * 2) * K + k0 + kq * 4;
      } else {
        aoff = (long)gm * K + k0 + kq * 4;
      }
      float4 v;
      if constexpr (std::is_same<AT, __hip_bfloat16>::value) {
        union { ushort4 u; __hip_bfloat16 h4[4]; } ld;
        ld.u = *(const ushort4*)(A + aoff);
        v = make_float4(__bfloat162float(ld.h4[0]), __bfloat162float(ld.h4[1]),
                        __bfloat162float(ld.h4[2]), __bfloat162float(ld.h4[3]));
      } else {
        v = *(const float4*)(A + aoff);
      }
      if constexpr (AMODE == 2) {
        v.x = hswish(v.x); v.y = hswish(v.y); v.z = hswish(v.z); v.w = hswish(v.w);
      }
      As[kq * 4 + 0][row] = v.x;
      As[kq * 4 + 1][row] = v.y;
      As[kq * 4 + 2][row] = v.z;
      As[kq * 4 + 3][row] = v.w;
    }
    #pragma unroll
    for (int l = 0; l < (BN * 4) / 256; ++l) {
      int f = tid + l * 256;
      int col4 = f & (BN / 4 - 1);
      int krow = f / (BN / 4);
      *(float4*)&Bs[krow][col4 * 4] =
          *(const float4*)(Bm + (long)(k0 + krow) * N + n0 + col4 * 4);
    }
    __syncthreads();
    #pragma unroll
    for (int kk = 0; kk < 16; ++kk) {
      float4 a0 = *(const float4*)&As[kk][ty * 4];
      float4 b0 = *(const float4*)&Bs[kk][tx * 4];
      fma4x4(acc[0][0], a0, b0);
      if constexpr (RN > 1) {
        float4 b1 = *(const float4*)&Bs[kk][tx * 4 + 64];
        fma4x4(acc[0][1], a0, b1);
        if constexpr (RM > 1) {
          float4 a1 = *(const float4*)&As[kk][ty * 4 + 64];
          fma4x4(acc[1][0], a1, b0);
          fma4x4(acc[1][1], a1, b1);
        }
      } else if constexpr (RM > 1) {
        float4 a1 = *(const float4*)&As[kk][ty * 4 + 64];
        fma4x4(acc[1][0], a1, b0);
      }
    }
    __syncthreads();
  }

  #pragma unroll
  for (int i = 0; i < RM; ++i) {
    #pragma unroll
    for (int r = 0; r < 4; ++r) {
      int row = m0 + i * 64 + ty * 4 + r;
      #pragma unroll
      for (int j = 0; j < RN; ++j) {
        int col = n0 + j * 64 + tx * 4;
        if constexpr (EPI == 0) {
          *(float4*)((float*)Cout + (long)row * N + col) =
              make_float4(acc[i][j][r][0], acc[i][j][r][1], acc[i][j][r][2], acc[i][j][r][3]);
        } else {
          float4 a4 = *(const float4*)(ea + col);
          float4 b4 = *(const float4*)(eb + col);
          union { ushort4 u; __hip_bfloat16 h4[4]; } pk;
          pk.h4[0] = __float2bfloat16(acc[i][j][r][0] * a4.x + b4.x);
          pk.h4[1] = __float2bfloat16(acc[i][j][r][1] * a4.y + b4.y);
          pk.h4[2] = __float2bfloat16(acc[i][j][r][2] * a4.z + b4.z);
          pk.h4[3] = __float2bfloat16(acc[i][j][r][3] * a4.w + b4.w);
          *(ushort4*)((__hip_bfloat16*)Cout + (long)row * N + col) = pk.u;
        }
      }
    }
  }
}

// ---------------------------------------------------------------------------
// Flash attention. Block = (qtile 49 rows, head, batch), 256 threads.
// KV and Q are pre-normalized bf16. Online softmax over 14 key tiles of 56.
// ---------------------------------------------------------------------------
__global__ __launch_bounds__(256) void attn_kernel(
    const __hip_bfloat16* __restrict__ kv, const __hip_bfloat16* __restrict__ qn,
    const float* __restrict__ bias, __hip_bfloat16* __restrict__ O) {
  const int qt = blockIdx.x, h = blockIdx.y, b = blockIdx.z;
  const int tid = threadIdx.x;

  __shared__ __align__(16) float qst[64][52];  // q^T (49 rows, pad to 52)
  __shared__ __align__(16) float kst[64][56];  // k^T tile (56 keys)
  __shared__ __align__(16) float pS[52][68];   // scores / probs
  __shared__ float mrow[52], lrow[52], frow[52];

  if (tid < 52) { mrow[tid] = -1e30f; lrow[tid] = 0.f; frow[tid] = 1.f; }

  for (int f = tid; f < 49 * 16; f += 256) {
    int r = f >> 4, d4 = f & 15;
    union { ushort4 u; __hip_bfloat16 h4[4]; } ld;
    ld.u = *(const ushort4*)(qn + (long)(b * 196 + qt * 49 + r) * 768 + h * 64 + d4 * 4);
    #pragma unroll
    for (int j = 0; j < 4; ++j) qst[d4 * 4 + j][r] = __bfloat162float(ld.h4[j]);
  }
  if (tid < 192) { int d = tid & 63, j = tid >> 6; qst[d][49 + j] = 0.f; }

  float o[49];
  #pragma unroll
  for (int r = 0; r < 49; ++r) o[r] = 0.f;

  __syncthreads();

  for (int kt = 0; kt < 14; ++kt) {
    const int k0 = kt * 56;
    for (int f = tid; f < 56 * 16; f += 256) {
      int kk = f >> 4, d4 = f & 15;
      union { ushort4 u; __hip_bfloat16 h4[4]; } ld;
      ld.u = *(const ushort4*)(kv + (long)(b * 784 + k0 + kk) * 3840 + h * 64 + d4 * 4);
      #pragma unroll
      for (int j = 0; j < 4; ++j) kst[d4 * 4 + j][kk] = __bfloat162float(ld.h4[j]);
    }
    __syncthreads();
    // scores: 13 rowgroups x 14 keygroups of 4x4
    if (tid < 182) {
      int rg = tid / 14, kg = tid - rg * 14;
      int r0 = rg * 4, kk0 = kg * 4;
      float sc[4][4] = {};
      #pragma unroll 16
      for (int i = 0; i < 64; ++i) {
        float4 qv = *(const float4*)&qst[i][r0];
        float4 kf = *(const float4*)&kst[i][kk0];
        fma4x4(sc, qv, kf);
      }
      #pragma unroll
      for (int j = 0; j < 4; ++j) {
        int r = r0 + j;
        if (r < 49) {
          const float* bp = bias + (long)(qt * 49 + r) * 784 + k0 + kk0;
          float4 pv;
          pv.x = sc[j][0] * 0.125f + bp[0];
          pv.y = sc[j][1] * 0.125f + bp[1];
          pv.z = sc[j][2] * 0.125f + bp[2];
          pv.w = sc[j][3] * 0.125f + bp[3];
          *(float4*)&pS[r][kk0] = pv;
        }
      }
    }
    __syncthreads();
    // online softmax (one thread per q row)
    if (tid < 49) {
      int r = tid;
      float mold = mrow[r];
      float mx = mold;
      #pragma unroll
      for (int c4 = 0; c4 < 14; ++c4) {
        float4 v = *(const float4*)&pS[r][c4 * 4];
        mx = fmaxf(mx, fmaxf(fmaxf(v.x, v.y), fmaxf(v.z, v.w)));
      }
      float f = __expf(mold - mx);
      float sum = 0.f;
      #pragma unroll
      for (int c4 = 0; c4 < 14; ++c4) {
        float4 v = *(const float4*)&pS[r][c4 * 4];
        v.x = __expf(v.x - mx); v.y = __expf(v.y - mx);
        v.z = __expf(v.z - mx); v.w = __expf(v.w - mx);
        sum += v.x + v.y + v.z + v.w;
        *(float4*)&pS[r][c4 * 4] = v;
      }
      mrow[r] = mx; frow[r] = f; lrow[r] = lrow[r] * f + sum;
    }
    __syncthreads();
    // PV: thread owns v-dim d = tid of this head's 256-wide slice
    float vr[56];
    #pragma unroll
    for (int kk = 0; kk < 56; ++kk) {
      vr[kk] = __bfloat162float(kv[(long)(b * 784 + k0 + kk) * 3840 + 768 + h * 256 + tid]);
    }
    #pragma unroll
    for (int r = 0; r < 49; ++r) {
      float orow = o[r] * frow[r];
      #pragma unroll
      for (int c4 = 0; c4 < 14; ++c4) {
        float4 pv = *(const float4*)&pS[r][c4 * 4];
        orow += pv.x * vr[c4 * 4 + 0] + pv.y * vr[c4 * 4 + 1] +
                pv.z * vr[c4 * 4 + 2] + pv.w * vr[c4 * 4 + 3];
      }
      o[r] = orow;
    }
    __syncthreads();
  }

  #pragma unroll
  for (int r = 0; r < 49; ++r) {
    O[(long)(b * 196 + qt * 49 + r) * 3072 + h * 256 + tid] =
        __float2bfloat16(o[r] / lrow[r]);
  }
}

// ---------------------------------------------------------------------------
extern "C" void kernel_launch(void* const* d_in, const int* in_sizes, int n_in,
                              void* d_out, int out_size, void* d_ws, size_t ws_size,
                              hipStream_t stream) {
  if (ws_size < WS_TOTAL) return;  // diagnostic: absmax will equal max|ref|

  const float* x    = (const float*)d_in[0];
  const float* Wqkv = (const float*)d_in[1];
  const float* bn1s = (const float*)d_in[2];
  const float* Wq   = (const float*)d_in[3];
  const float* bn2s = (const float*)d_in[4];
  const float* bias = (const float*)d_in[5];
  const float* Wout = (const float*)d_in[6];

  char* ws = (char*)d_ws;
  __hip_bfloat16* kvb = (__hip_bfloat16*)(ws + OFF_KV);
  __hip_bfloat16* qnb = (__hip_bfloat16*)(ws + OFF_QN);
  __hip_bfloat16* Ob  = (__hip_bfloat16*)(ws + OFF_O);
  float* ps1  = (float*)(ws + OFF_PS1);
  float* pcs1 = (float*)(ws + OFF_PCS1);
  float* ps2  = (float*)(ws + OFF_PS2);
  float* pcs2 = (float*)(ws + OFF_PCS2);
  float* sx1  = (float*)(ws + OFF_SX1);
  float* cs1  = (float*)(ws + OFF_CS1);
  float* sx2  = (float*)(ws + OFF_SX2);
  float* cs2  = (float*)(ws + OFF_CS2);
  float* a1w  = (float*)(ws + OFF_A1);
  float* b1w  = (float*)(ws + OFF_B1);
  float* a2w  = (float*)(ws + OFF_A2);
  float* b2w  = (float*)(ws + OFF_B2);
  float* out  = (float*)d_out;

  // 1-2. split-K X^T X partials (+ colsums)
  xtx_partial<0><<<dim3(36, CH1), 256, 0, stream>>>(x, ps1, pcs1, M1 / CH1);
  xtx_partial<1><<<dim3(36, CH2), 256, 0, stream>>>(x, ps2, pcs2, M2 / CH2);
  reduce_chunks<<<dim3(576), 256, 0, stream>>>(ps1, sx1, 384 * 384, CH1);
  reduce_chunks<<<dim3(2),   256, 0, stream>>>(pcs1, cs1, 384, CH1);
  reduce_chunks<<<dim3(576), 256, 0, stream>>>(ps2, sx2, 384 * 384, CH2);
  reduce_chunks<<<dim3(2),   256, 0, stream>>>(pcs2, cs2, 384, CH2);
  // 3. analytic BN coefficients
  bnprep<<<dim3(3840), 256, 0, stream>>>(Wqkv, sx1, cs1, bn1s, a1w, b1w, N1, 1.f / (float)M1);
  bnprep<<<dim3(768),  256, 0, stream>>>(Wq,   sx2, cs2, bn2s, a2w, b2w, Dq, 1.f / (float)M2);
  // 4. KV = BN(x @ W_qkv) -> bf16
  gemm_f32<float, 128, 128, 0, 1><<<dim3(30, 196), 256, 0, stream>>>(
      x, Wqkv, kvb, a1w, b1w, N1, Kc);
  // 5. Qn = BN(x' @ W_q) -> bf16
  gemm_f32<float, 64, 128, 1, 1><<<dim3(6, 98), 256, 0, stream>>>(
      x, Wq, qnb, a2w, b2w, Dq, Kc);
  // 6. attention -> O bf16
  attn_kernel<<<dim3(4, 12, 32), 256, 0, stream>>>(kvb, qnb, bias, Ob);
  // 7. out = hard_swish(O) @ W_out
  gemm_f32<__hip_bfloat16, 64, 128, 2, 0><<<dim3(4, 98), 256, 0, stream>>>(
      Ob, Wout, out, nullptr, nullptr, OUTD, 3072);
}

// Round 3
// 2136.910 us; speedup vs baseline: 3.1085x; 3.1085x over previous
//
#include <hip/hip_runtime.h>
#include <hip/hip_bf16.h>
#include <type_traits>

// ---------------------------------------------------------------------------
// LeViT subsample attention (round 2): MFMA flash attention.
//   1. Sx = x^T x (+colsum) split-K partials -> analytic BN coefficients
//   2. GEMM1: KV = BN(x @ W_qkv) -> normalized bf16
//   3. qGEMM: Qn = BN(x' @ W_q)  -> normalized bf16
//   4. attn_mfma: two-pass flash attention, 16x16x32 bf16 MFMA -> O bf16
//   5. out = hard_swish(O) @ W_out -> f32
// ---------------------------------------------------------------------------

static constexpr int M1 = 25088, N1 = 3840, Kc = 384;
static constexpr int M2 = 6272, Dq = 768, OUTD = 512;
static constexpr int CH1 = 14, CH2 = 7;

static constexpr size_t OFF_KV   = 0;            // bf16 25088x3840
static constexpr size_t OFF_QN   = 192675840;    // bf16 6272x768
static constexpr size_t OFF_O    = 202309632;    // bf16 6272x3072
static constexpr size_t OFF_PS1  = 240844800;    // f32 14x384x384
static constexpr size_t OFF_PCS1 = 249102336;    // f32 14x384
static constexpr size_t OFF_PS2  = 249123840;    // f32 7x384x384
static constexpr size_t OFF_PCS2 = 253252608;    // f32 7x384
static constexpr size_t OFF_SX1  = 253263360;
static constexpr size_t OFF_CS1  = 253853184;
static constexpr size_t OFF_SX2  = 253854720;
static constexpr size_t OFF_CS2  = 254444544;
static constexpr size_t OFF_A1   = 254446080;
static constexpr size_t OFF_B1   = 254461440;
static constexpr size_t OFF_A2   = 254476800;
static constexpr size_t OFF_B2   = 254479872;
static constexpr size_t WS_TOTAL = 254482944;

typedef __attribute__((ext_vector_type(8))) short bf16x8;
typedef __attribute__((ext_vector_type(4))) float f32x4;

static __device__ __forceinline__ f32x4 mfma16(bf16x8 a, bf16x8 b, f32x4 c) {
  return __builtin_amdgcn_mfma_f32_16x16x32_bf16(a, b, c, 0, 0, 0);
}

__device__ __forceinline__ float hswish(float x) {
  float t = fminf(fmaxf(x + 3.0f, 0.0f), 6.0f);
  return x * t * (1.0f / 6.0f);
}

__device__ __forceinline__ void fma4x4(float (&c)[4][4], const float4 a, const float4 b) {
  c[0][0] += a.x*b.x; c[0][1] += a.x*b.y; c[0][2] += a.x*b.z; c[0][3] += a.x*b.w;
  c[1][0] += a.y*b.x; c[1][1] += a.y*b.y; c[1][2] += a.y*b.z; c[1][3] += a.y*b.w;
  c[2][0] += a.z*b.x; c[2][1] += a.z*b.y; c[2][2] += a.z*b.z; c[2][3] += a.z*b.w;
  c[3][0] += a.w*b.x; c[3][1] += a.w*b.y; c[3][2] += a.w*b.z; c[3][3] += a.w*b.w;
}

// --------------------------- X^T X partials --------------------------------
template<int GATHER>
__global__ __launch_bounds__(256) void xtx_partial(
    const float* __restrict__ X, float* __restrict__ pS, float* __restrict__ pcs,
    int rows_per_chunk) {
  const int ti = blockIdx.x / 6, tj = blockIdx.x % 6;
  const int chunk = blockIdx.y;
  const int tid = threadIdx.x;
  const int tx = tid & 15, ty = tid >> 4;
  __shared__ __align__(16) float xa[32][64];
  __shared__ __align__(16) float xb[32][64];
  __shared__ float redcs[256];
  float acc[4][4] = {};
  float cs = 0.f;
  const int cq = tid & 63, rq = tid >> 6;

  for (int rr = 0; rr < rows_per_chunk; rr += 32) {
    #pragma unroll
    for (int l = 0; l < 2; ++l) {
      int f = tid + l * 256;
      int r = f >> 4, c4 = f & 15;
      int m = chunk * rows_per_chunk + rr + r;
      long grow;
      if constexpr (GATHER) {
        int bb = m / 196, t = m - bb * 196;
        int h2 = t / 14, w2 = t - h2 * 14;
        grow = (long)(bb * 784 + h2 * 56 + w2 * 2);
      } else {
        grow = m;
      }
      const float* src = X + grow * 384;
      *(float4*)&xa[r][c4 * 4] = *(const float4*)(src + ti * 64 + c4 * 4);
      *(float4*)&xb[r][c4 * 4] = *(const float4*)(src + tj * 64 + c4 * 4);
    }
    __syncthreads();
    if (ti == 0) {
      #pragma unroll
      for (int r = 0; r < 8; ++r) cs += xb[rq * 8 + r][cq];
    }
    #pragma unroll
    for (int r = 0; r < 32; ++r) {
      float4 av = *(const float4*)&xa[r][ty * 4];
      float4 bv = *(const float4*)&xb[r][tx * 4];
      fma4x4(acc, av, bv);
    }
    __syncthreads();
  }
  #pragma unroll
  for (int r = 0; r < 4; ++r) {
    *(float4*)(pS + ((long)chunk * 384 + ti * 64 + ty * 4 + r) * 384 + tj * 64 + tx * 4) =
        make_float4(acc[r][0], acc[r][1], acc[r][2], acc[r][3]);
  }
  if (ti == 0) {
    redcs[tid] = cs;
    __syncthreads();
    if (tid < 64) {
      pcs[(long)chunk * 384 + tj * 64 + tid] =
          redcs[tid] + redcs[tid + 64] + redcs[tid + 128] + redcs[tid + 192];
    }
  }
}

__global__ __launch_bounds__(256) void reduce_chunks(
    const float* __restrict__ src, float* __restrict__ dst, int nelem, int nchunks) {
  int i = blockIdx.x * 256 + threadIdx.x;
  if (i >= nelem) return;
  float s = 0.f;
  for (int c = 0; c < nchunks; ++c) s += src[(long)c * nelem + i];
  dst[i] = s;
}

__global__ __launch_bounds__(256) void bnprep(
    const float* __restrict__ W, const float* __restrict__ Sx, const float* __restrict__ cs,
    const float* __restrict__ scale, float* __restrict__ a, float* __restrict__ b,
    int N, float invM) {
  const int j = blockIdx.x;
  __shared__ __align__(16) float wj[384];
  __shared__ float red[256], red2[256];
  for (int k = threadIdx.x; k < 384; k += 256) wj[k] = W[(long)k * N + j];
  __syncthreads();
  float yy = 0.f, mu = 0.f;
  for (int k = threadIdx.x; k < 384; k += 256) {
    float rowdot = 0.f;
    const float* srow = Sx + (long)k * 384;
    #pragma unroll 8
    for (int l = 0; l < 384; l += 4) {
      float4 s = *(const float4*)(srow + l);
      float4 w = *(const float4*)(&wj[l]);
      rowdot += s.x*w.x + s.y*w.y + s.z*w.z + s.w*w.w;
    }
    yy += wj[k] * rowdot;
    mu += cs[k] * wj[k];
  }
  red[threadIdx.x] = yy; red2[threadIdx.x] = mu;
  __syncthreads();
  for (int s = 128; s > 0; s >>= 1) {
    if (threadIdx.x < s) { red[threadIdx.x] += red[threadIdx.x + s]; red2[threadIdx.x] += red2[threadIdx.x + s]; }
    __syncthreads();
  }
  if (threadIdx.x == 0) {
    float mean = red2[0] * invM;
    float var = red[0] * invM - mean * mean;
    float ai = rsqrtf(var + 1e-5f) * scale[j];
    a[j] = ai;
    b[j] = -mean * ai;
  }
}

// ------------------------------- GEMM --------------------------------------
template<typename AT, int BM, int BN, int AMODE, int EPI>
__global__ __launch_bounds__(256) void gemm_f32(
    const AT* __restrict__ A, const float* __restrict__ Bm, void* __restrict__ Cout,
    const float* __restrict__ ea, const float* __restrict__ eb, int N, int K) {
  constexpr int RM = BM / 64, RN = BN / 64;
  __shared__ __align__(16) float As[16][BM];
  __shared__ __align__(16) float Bs[16][BN];
  const int tid = threadIdx.x;
  const int n0 = blockIdx.x * BN, m0 = blockIdx.y * BM;
  const int tx = tid & 15, ty = tid >> 4;
  float acc[RM][RN][4][4] = {};

  for (int k0 = 0; k0 < K; k0 += 16) {
    #pragma unroll
    for (int l = 0; l < (BM * 4) / 256; ++l) {
      int f = tid + l * 256;
      int row = f >> 2, kq = f & 3;
      int gm = m0 + row;
      long aoff;
      if constexpr (AMODE == 1) {
        int bb = gm / 196, t = gm - bb * 196;
        int h2 = t / 14, w2 = t - h2 * 14;
        aoff = (long)(bb * 784 + h2 * 56 + w2 * 2) * K + k0 + kq * 4;
      } else {
        aoff = (long)gm * K + k0 + kq * 4;
      }
      float4 v;
      if constexpr (std::is_same<AT, __hip_bfloat16>::value) {
        union { ushort4 u; __hip_bfloat16 h4[4]; } ld;
        ld.u = *(const ushort4*)(A + aoff);
        v = make_float4(__bfloat162float(ld.h4[0]), __bfloat162float(ld.h4[1]),
                        __bfloat162float(ld.h4[2]), __bfloat162float(ld.h4[3]));
      } else {
        v = *(const float4*)(A + aoff);
      }
      if constexpr (AMODE == 2) {
        v.x = hswish(v.x); v.y = hswish(v.y); v.z = hswish(v.z); v.w = hswish(v.w);
      }
      As[kq * 4 + 0][row] = v.x;
      As[kq * 4 + 1][row] = v.y;
      As[kq * 4 + 2][row] = v.z;
      As[kq * 4 + 3][row] = v.w;
    }
    #pragma unroll
    for (int l = 0; l < (BN * 4) / 256; ++l) {
      int f = tid + l * 256;
      int col4 = f & (BN / 4 - 1);
      int krow = f / (BN / 4);
      *(float4*)&Bs[krow][col4 * 4] =
          *(const float4*)(Bm + (long)(k0 + krow) * N + n0 + col4 * 4);
    }
    __syncthreads();
    #pragma unroll
    for (int kk = 0; kk < 16; ++kk) {
      float4 a0 = *(const float4*)&As[kk][ty * 4];
      float4 b0 = *(const float4*)&Bs[kk][tx * 4];
      fma4x4(acc[0][0], a0, b0);
      if constexpr (RN > 1) {
        float4 b1 = *(const float4*)&Bs[kk][tx * 4 + 64];
        fma4x4(acc[0][1], a0, b1);
        if constexpr (RM > 1) {
          float4 a1 = *(const float4*)&As[kk][ty * 4 + 64];
          fma4x4(acc[1][0], a1, b0);
          fma4x4(acc[1][1], a1, b1);
        }
      } else if constexpr (RM > 1) {
        float4 a1 = *(const float4*)&As[kk][ty * 4 + 64];
        fma4x4(acc[1][0], a1, b0);
      }
    }
    __syncthreads();
  }

  #pragma unroll
  for (int i = 0; i < RM; ++i) {
    #pragma unroll
    for (int r = 0; r < 4; ++r) {
      int row = m0 + i * 64 + ty * 4 + r;
      #pragma unroll
      for (int j = 0; j < RN; ++j) {
        int col = n0 + j * 64 + tx * 4;
        if constexpr (EPI == 0) {
          *(float4*)((float*)Cout + (long)row * N + col) =
              make_float4(acc[i][j][r][0], acc[i][j][r][1], acc[i][j][r][2], acc[i][j][r][3]);
        } else {
          float4 a4 = *(const float4*)(ea + col);
          float4 b4 = *(const float4*)(eb + col);
          union { ushort4 u; __hip_bfloat16 h4[4]; } pk;
          pk.h4[0] = __float2bfloat16(acc[i][j][r][0] * a4.x + b4.x);
          pk.h4[1] = __float2bfloat16(acc[i][j][r][1] * a4.y + b4.y);
          pk.h4[2] = __float2bfloat16(acc[i][j][r][2] * a4.z + b4.z);
          pk.h4[3] = __float2bfloat16(acc[i][j][r][3] * a4.w + b4.w);
          *(ushort4*)((__hip_bfloat16*)Cout + (long)row * N + col) = pk.u;
        }
      }
    }
  }
}

// ---------------------------------------------------------------------------
// MFMA flash attention. Block = (qt in {0,1}: 112 q rows, h, b), 512 threads
// = 8 waves. Two passes over 13 key tiles of KT=64:
//   pass 1: S = Q K^T (16x16x32 MFMA), row max -> marr
//   pass 2: P = exp(S/8 + bias - m) -> bf16 LDS; O += P V via MFMA on V^T.
// Wave w: score n-tile (w&3), m-tiles {w>>2, +2, +4(,6)}; PV dv-slice w*32.
// K tile and V^T tile share one LDS buffer (union in time).
// ---------------------------------------------------------------------------
__global__ __launch_bounds__(512) void attn_mfma(
    const __hip_bfloat16* __restrict__ kv, const __hip_bfloat16* __restrict__ qn,
    const float* __restrict__ bias, __hip_bfloat16* __restrict__ O) {
  const int qt = blockIdx.x, h = blockIdx.y, b = blockIdx.z;
  const int tid = threadIdx.x;
  const int w = tid >> 6;          // wave 0..7
  const int lane = tid & 63;
  const int cl = lane & 15;        // frag col
  const int kg = lane >> 4;        // frag k-group / row-group
  const int kb = kg * 8;
  const int qbase = qt * 112;
  const int valid = 196 - qbase > 112 ? 112 : 196 - qbase;   // 112 or 84

  __shared__ __align__(16) short Qs[112][72];
  __shared__ __align__(16) short KVs[256][72];   // K tile rows 0-63 / V^T all
  __shared__ __align__(16) short pPs[112][72];
  __shared__ float marr[112], lsum[112];
  __shared__ float pred[8][112];

  const bf16x8 zero8 = {0,0,0,0,0,0,0,0};
  const f32x4 zerof = {0.f,0.f,0.f,0.f};

  // ---- stage Q (rows >= valid zeroed), init m/l ----
  for (int f = tid; f < 896; f += 512) {
    int row = f >> 3, d8 = f & 7;
    bf16x8 v = zero8;
    if (row < valid) {
      v = *(const bf16x8*)(qn + (long)(b * 196 + qbase + row) * 768 + h * 64 + d8 * 8);
    }
    *(bf16x8*)&Qs[row][d8 * 8] = v;
  }
  if (tid < 112) { marr[tid] = -1e30f; lsum[tid] = 0.f; }
  __syncthreads();

  const int mt0 = w >> 2, snt = w & 3;

  // =============================== pass 1 ==================================
  for (int kt = 0; kt < 13; ++kt) {
    const int k0 = kt * 64;
    // stage K tile [64][64] -> KVs rows 0..63
    {
      int kk = tid >> 3, d8 = tid & 7;
      bf16x8 v = zero8;
      if (k0 + kk < 784) {
        v = *(const bf16x8*)(kv + (long)(b * 784 + k0 + kk) * 3840 + h * 64 + d8 * 8);
      }
      *(bf16x8*)&KVs[kk][d8 * 8] = v;
    }
    __syncthreads();
    #pragma unroll
    for (int i = 0; i < 4; ++i) {
      int mt = mt0 + 2 * i;
      if (mt >= 7) break;
      bf16x8 a0 = *(const bf16x8*)&Qs[mt * 16 + cl][kb];
      bf16x8 a1 = *(const bf16x8*)&Qs[mt * 16 + cl][32 + kb];
      bf16x8 b0 = *(const bf16x8*)&KVs[snt * 16 + cl][kb];
      bf16x8 b1 = *(const bf16x8*)&KVs[snt * 16 + cl][32 + kb];
      f32x4 s = mfma16(a1, b1, mfma16(a0, b0, zerof));
      #pragma unroll
      for (int r = 0; r < 4; ++r) {
        float v = s[r] * 0.125f;
        v = fmaxf(v, __shfl_xor(v, 1));
        v = fmaxf(v, __shfl_xor(v, 2));
        v = fmaxf(v, __shfl_xor(v, 4));
        v = fmaxf(v, __shfl_xor(v, 8));
        if (cl == 0) pred[w][mt * 16 + kg * 4 + r] = v;
      }
    }
    __syncthreads();
    if (tid < 112) {
      int wb = ((tid >> 4) & 1) * 4;
      float m = fmaxf(fmaxf(pred[wb][tid], pred[wb + 1][tid]),
                      fmaxf(pred[wb + 2][tid], pred[wb + 3][tid]));
      marr[tid] = fmaxf(marr[tid], m);
    }
  }

  // =============================== pass 2 ==================================
  f32x4 acc[7][2];
  #pragma unroll
  for (int mt = 0; mt < 7; ++mt) { acc[mt][0] = zerof; acc[mt][1] = zerof; }

  for (int kt = 0; kt < 13; ++kt) {
    const int k0 = kt * 64;
    __syncthreads();   // PV of prev tile done before overwriting KVs
    {
      int kk = tid >> 3, d8 = tid & 7;
      bf16x8 v = zero8;
      if (k0 + kk < 784) {
        v = *(const bf16x8*)(kv + (long)(b * 784 + k0 + kk) * 3840 + h * 64 + d8 * 8);
      }
      *(bf16x8*)&KVs[kk][d8 * 8] = v;
    }
    __syncthreads();
    // scores -> P(bf16) -> pPs; per-wave row-sum partials -> pred
    #pragma unroll
    for (int i = 0; i < 4; ++i) {
      int mt = mt0 + 2 * i;
      if (mt >= 7) break;
      bf16x8 a0 = *(const bf16x8*)&Qs[mt * 16 + cl][kb];
      bf16x8 a1 = *(const bf16x8*)&Qs[mt * 16 + cl][32 + kb];
      bf16x8 b0 = *(const bf16x8*)&KVs[snt * 16 + cl][kb];
      bf16x8 b1 = *(const bf16x8*)&KVs[snt * 16 + cl][32 + kb];
      f32x4 s = mfma16(a1, b1, mfma16(a0, b0, zerof));
      int key = k0 + snt * 16 + cl;
      #pragma unroll
      for (int r = 0; r < 4; ++r) {
        int rl = mt * 16 + kg * 4 + r;
        int qrow = qbase + rl;
        bool ok = (qrow < 196) && (key < 784);
        float bb = ok ? bias[(long)qrow * 784 + key] : 0.f;
        float p = ok ? __expf(s[r] * 0.125f + bb - marr[rl]) : 0.f;
        float ps = p;
        ps += __shfl_xor(ps, 1);
        ps += __shfl_xor(ps, 2);
        ps += __shfl_xor(ps, 4);
        ps += __shfl_xor(ps, 8);
        if (cl == 0) pred[w][rl] = ps;
        __hip_bfloat16 pb = __float2bfloat16(p);
        pPs[rl][snt * 16 + cl] = *(short*)&pb;
      }
    }
    __syncthreads();
    // stage V^T (overwrites K region): Vt[dv][kk] with col-group XOR swizzle
    #pragma unroll
    for (int l = 0; l < 4; ++l) {
      int f = tid + l * 512;
      int dv8 = f & 31, kk = f >> 5;
      union { uint4 u; short s[8]; } vv;
      if (k0 + kk < 784) {
        vv.u = *(const uint4*)(kv + (long)(b * 784 + k0 + kk) * 3840 + 768 + h * 256 + dv8 * 8);
      } else {
        vv.u = make_uint4(0, 0, 0, 0);
      }
      int col = (((kk >> 3) ^ (dv8 & 7)) << 3) | (kk & 7);
      #pragma unroll
      for (int j = 0; j < 8; ++j) KVs[dv8 * 8 + j][col] = vv.s[j];
    }
    __syncthreads();
    if (tid < 112) {
      int wb = ((tid >> 4) & 1) * 4;
      lsum[tid] += pred[wb][tid] + pred[wb + 1][tid] + pred[wb + 2][tid] + pred[wb + 3][tid];
    }
    // PV: wave w owns dv slice [w*32, w*32+32)
    #pragma unroll
    for (int mt = 0; mt < 7; ++mt) {
      #pragma unroll
      for (int kc = 0; kc < 2; ++kc) {
        bf16x8 a = *(const bf16x8*)&pPs[mt * 16 + cl][kc * 32 + kb];
        int g = kc * 4 + kg;
        #pragma unroll
        for (int nt2 = 0; nt2 < 2; ++nt2) {
          int dv = w * 32 + nt2 * 16 + cl;
          bf16x8 bv = *(const bf16x8*)&KVs[dv][(g ^ ((dv >> 3) & 7)) << 3];
          acc[mt][nt2] = mfma16(a, bv, acc[mt][nt2]);
        }
      }
    }
  }
  __syncthreads();

  // ---- store O ----
  #pragma unroll
  for (int mt = 0; mt < 7; ++mt) {
    #pragma unroll
    for (int r = 0; r < 4; ++r) {
      int rl = mt * 16 + kg * 4 + r;
      if (rl < valid) {
        float li = 1.0f / lsum[rl];
        #pragma unroll
        for (int nt2 = 0; nt2 < 2; ++nt2) {
          float ov = acc[mt][nt2][r] * li;
          O[(long)(b * 196 + qbase + rl) * 3072 + h * 256 + w * 32 + nt2 * 16 + cl] =
              __float2bfloat16(ov);
        }
      }
    }
  }
}

// ---------------------------------------------------------------------------
extern "C" void kernel_launch(void* const* d_in, const int* in_sizes, int n_in,
                              void* d_out, int out_size, void* d_ws, size_t ws_size,
                              hipStream_t stream) {
  if (ws_size < WS_TOTAL) return;

  const float* x    = (const float*)d_in[0];
  const float* Wqkv = (const float*)d_in[1];
  const float* bn1s = (const float*)d_in[2];
  const float* Wq   = (const float*)d_in[3];
  const float* bn2s = (const float*)d_in[4];
  const float* bias = (const float*)d_in[5];
  const float* Wout = (const float*)d_in[6];

  char* ws = (char*)d_ws;
  __hip_bfloat16* kvb = (__hip_bfloat16*)(ws + OFF_KV);
  __hip_bfloat16* qnb = (__hip_bfloat16*)(ws + OFF_QN);
  __hip_bfloat16* Ob  = (__hip_bfloat16*)(ws + OFF_O);
  float* ps1  = (float*)(ws + OFF_PS1);
  float* pcs1 = (float*)(ws + OFF_PCS1);
  float* ps2  = (float*)(ws + OFF_PS2);
  float* pcs2 = (float*)(ws + OFF_PCS2);
  float* sx1  = (float*)(ws + OFF_SX1);
  float* cs1  = (float*)(ws + OFF_CS1);
  float* sx2  = (float*)(ws + OFF_SX2);
  float* cs2  = (float*)(ws + OFF_CS2);
  float* a1w  = (float*)(ws + OFF_A1);
  float* b1w  = (float*)(ws + OFF_B1);
  float* a2w  = (float*)(ws + OFF_A2);
  float* b2w  = (float*)(ws + OFF_B2);
  float* out  = (float*)d_out;

  xtx_partial<0><<<dim3(36, CH1), 256, 0, stream>>>(x, ps1, pcs1, M1 / CH1);
  xtx_partial<1><<<dim3(36, CH2), 256, 0, stream>>>(x, ps2, pcs2, M2 / CH2);
  reduce_chunks<<<dim3(576), 256, 0, stream>>>(ps1, sx1, 384 * 384, CH1);
  reduce_chunks<<<dim3(2),   256, 0, stream>>>(pcs1, cs1, 384, CH1);
  reduce_chunks<<<dim3(576), 256, 0, stream>>>(ps2, sx2, 384 * 384, CH2);
  reduce_chunks<<<dim3(2),   256, 0, stream>>>(pcs2, cs2, 384, CH2);
  bnprep<<<dim3(3840), 256, 0, stream>>>(Wqkv, sx1, cs1, bn1s, a1w, b1w, N1, 1.f / (float)M1);
  bnprep<<<dim3(768),  256, 0, stream>>>(Wq,   sx2, cs2, bn2s, a2w, b2w, Dq, 1.f / (float)M2);
  gemm_f32<float, 128, 128, 0, 1><<<dim3(30, 196), 256, 0, stream>>>(
      x, Wqkv, kvb, a1w, b1w, N1, Kc);
  gemm_f32<float, 64, 128, 1, 1><<<dim3(6, 98), 256, 0, stream>>>(
      x, Wq, qnb, a2w, b2w, Dq, Kc);
  attn_mfma<<<dim3(2, 12, 32), 512, 0, stream>>>(kvb, qnb, bias, Ob);
  gemm_f32<__hip_bfloat16, 64, 128, 2, 0><<<dim3(4, 98), 256, 0, stream>>>(
      Ob, Wout, out, nullptr, nullptr, OUTD, 3072);
}

// Round 4
// 1211.856 us; speedup vs baseline: 5.4812x; 1.7633x over previous
//
#include <hip/hip_runtime.h>
#include <hip/hip_bf16.h>

// ---------------------------------------------------------------------------
// LeViT subsample attention (round 3): all GEMMs on bf16 MFMA.
//   1. Sx = x^T x (+colsum) split-K partials -> analytic BN coefficients (f32)
//   2. prep: x -> bf16; W_qkv/W_q/W_out -> transposed bf16 [N][K]
//   3. gemm_mfma: KV = BN(xb @ Wqkvt^T) -> bf16 ; Qn likewise (gathered rows)
//   4. attn_mfma: two-pass flash attention -> hswish(O) bf16
//   5. gemm_mfma: out = hswishO @ Woutt^T -> f32
// m97 structure: 128x128 tile, BK=64, global_load_lds(16B) with pre-swizzled
// source + XOR-swizzled ds_read_b128 (T2); swapped-operand MFMA for packed
// 8B C-stores.
// ---------------------------------------------------------------------------

static constexpr int M1 = 25088, N1 = 3840, Kc = 384;
static constexpr int M2 = 6272, Dq = 768, OUTD = 512;
static constexpr int CH1 = 14, CH2 = 7;

static constexpr size_t OFF_KV   = 0;            // bf16 25088x3840
static constexpr size_t OFF_QN   = 192675840;    // bf16 6272x768
static constexpr size_t OFF_O    = 202309632;    // bf16 6272x3072 (also x_bf16 early)
static constexpr size_t OFF_XB   = OFF_O;        // bf16 25088x384 (dead before O written)
static constexpr size_t OFF_PS1  = 240844800;    // f32 14x384x384 (dead after reduce)
static constexpr size_t OFF_WQKVT= 240844800;    // bf16 3840x384  (over PS1)
static constexpr size_t OFF_WQT  = 243793920;    // bf16 768x384
static constexpr size_t OFF_WOUTT= 244383744;    // bf16 512x3072  (ends 247529472 < PCS1)
static constexpr size_t OFF_PCS1 = 249102336;    // f32 14x384
static constexpr size_t OFF_PS2  = 249123840;    // f32 7x384x384
static constexpr size_t OFF_PCS2 = 253252608;    // f32 7x384
static constexpr size_t OFF_SX1  = 253263360;
static constexpr size_t OFF_CS1  = 253853184;
static constexpr size_t OFF_SX2  = 253854720;
static constexpr size_t OFF_CS2  = 254444544;
static constexpr size_t OFF_A1   = 254446080;
static constexpr size_t OFF_B1   = 254461440;
static constexpr size_t OFF_A2   = 254476800;
static constexpr size_t OFF_B2   = 254479872;
static constexpr size_t WS_TOTAL = 254482944;

typedef __attribute__((ext_vector_type(8))) short bf16x8;
typedef __attribute__((ext_vector_type(4))) float f32x4;

static __device__ __forceinline__ f32x4 mfma16(bf16x8 a, bf16x8 b, f32x4 c) {
  return __builtin_amdgcn_mfma_f32_16x16x32_bf16(a, b, c, 0, 0, 0);
}

__device__ __forceinline__ void gload_lds16(const void* g, void* l) {
  __builtin_amdgcn_global_load_lds(
      (const __attribute__((address_space(1))) unsigned int*)g,
      (__attribute__((address_space(3))) unsigned int*)l, 16, 0, 0);
}

__device__ __forceinline__ float hswish(float x) {
  float t = fminf(fmaxf(x + 3.0f, 0.0f), 6.0f);
  return x * t * (1.0f / 6.0f);
}

__device__ __forceinline__ void fma4x4(float (&c)[4][4], const float4 a, const float4 b) {
  c[0][0] += a.x*b.x; c[0][1] += a.x*b.y; c[0][2] += a.x*b.z; c[0][3] += a.x*b.w;
  c[1][0] += a.y*b.x; c[1][1] += a.y*b.y; c[1][2] += a.y*b.z; c[1][3] += a.y*b.w;
  c[2][0] += a.z*b.x; c[2][1] += a.z*b.y; c[2][2] += a.z*b.z; c[2][3] += a.z*b.w;
  c[3][0] += a.w*b.x; c[3][1] += a.w*b.y; c[3][2] += a.w*b.z; c[3][3] += a.w*b.w;
}

// --------------------------- X^T X partials (f32) --------------------------
template<int GATHER>
__global__ __launch_bounds__(256) void xtx_partial(
    const float* __restrict__ X, float* __restrict__ pS, float* __restrict__ pcs,
    int rows_per_chunk) {
  const int ti = blockIdx.x / 6, tj = blockIdx.x % 6;
  const int chunk = blockIdx.y;
  const int tid = threadIdx.x;
  const int tx = tid & 15, ty = tid >> 4;
  __shared__ __align__(16) float xa[32][64];
  __shared__ __align__(16) float xb[32][64];
  __shared__ float redcs[256];
  float acc[4][4] = {};
  float cs = 0.f;
  const int cq = tid & 63, rq = tid >> 6;

  for (int rr = 0; rr < rows_per_chunk; rr += 32) {
    #pragma unroll
    for (int l = 0; l < 2; ++l) {
      int f = tid + l * 256;
      int r = f >> 4, c4 = f & 15;
      int m = chunk * rows_per_chunk + rr + r;
      long grow;
      if constexpr (GATHER) {
        int bb = m / 196, t = m - bb * 196;
        int h2 = t / 14, w2 = t - h2 * 14;
        grow = (long)(bb * 784 + h2 * 56 + w2 * 2);
      } else {
        grow = m;
      }
      const float* src = X + grow * 384;
      *(float4*)&xa[r][c4 * 4] = *(const float4*)(src + ti * 64 + c4 * 4);
      *(float4*)&xb[r][c4 * 4] = *(const float4*)(src + tj * 64 + c4 * 4);
    }
    __syncthreads();
    if (ti == 0) {
      #pragma unroll
      for (int r = 0; r < 8; ++r) cs += xb[rq * 8 + r][cq];
    }
    #pragma unroll
    for (int r = 0; r < 32; ++r) {
      float4 av = *(const float4*)&xa[r][ty * 4];
      float4 bv = *(const float4*)&xb[r][tx * 4];
      fma4x4(acc, av, bv);
    }
    __syncthreads();
  }
  #pragma unroll
  for (int r = 0; r < 4; ++r) {
    *(float4*)(pS + ((long)chunk * 384 + ti * 64 + ty * 4 + r) * 384 + tj * 64 + tx * 4) =
        make_float4(acc[r][0], acc[r][1], acc[r][2], acc[r][3]);
  }
  if (ti == 0) {
    redcs[tid] = cs;
    __syncthreads();
    if (tid < 64) {
      pcs[(long)chunk * 384 + tj * 64 + tid] =
          redcs[tid] + redcs[tid + 64] + redcs[tid + 128] + redcs[tid + 192];
    }
  }
}

__global__ __launch_bounds__(256) void reduce_chunks(
    const float* __restrict__ src, float* __restrict__ dst, int nelem, int nchunks) {
  int i = blockIdx.x * 256 + threadIdx.x;
  if (i >= nelem) return;
  float s = 0.f;
  for (int c = 0; c < nchunks; ++c) s += src[(long)c * nelem + i];
  dst[i] = s;
}

__global__ __launch_bounds__(256) void bnprep(
    const float* __restrict__ W, const float* __restrict__ Sx, const float* __restrict__ cs,
    const float* __restrict__ scale, float* __restrict__ a, float* __restrict__ b,
    int N, float invM) {
  const int j = blockIdx.x;
  __shared__ __align__(16) float wj[384];
  __shared__ float red[256], red2[256];
  for (int k = threadIdx.x; k < 384; k += 256) wj[k] = W[(long)k * N + j];
  __syncthreads();
  float yy = 0.f, mu = 0.f;
  for (int k = threadIdx.x; k < 384; k += 256) {
    float rowdot = 0.f;
    const float* srow = Sx + (long)k * 384;
    #pragma unroll 8
    for (int l = 0; l < 384; l += 4) {
      float4 s = *(const float4*)(srow + l);
      float4 w = *(const float4*)(&wj[l]);
      rowdot += s.x*w.x + s.y*w.y + s.z*w.z + s.w*w.w;
    }
    yy += wj[k] * rowdot;
    mu += cs[k] * wj[k];
  }
  red[threadIdx.x] = yy; red2[threadIdx.x] = mu;
  __syncthreads();
  for (int s = 128; s > 0; s >>= 1) {
    if (threadIdx.x < s) { red[threadIdx.x] += red[threadIdx.x + s]; red2[threadIdx.x] += red2[threadIdx.x + s]; }
    __syncthreads();
  }
  if (threadIdx.x == 0) {
    float mean = red2[0] * invM;
    float var = red[0] * invM - mean * mean;
    float ai = rsqrtf(var + 1e-5f) * scale[j];
    a[j] = ai;
    b[j] = -mean * ai;
  }
}

// --------------------------- prep: convert / transpose ---------------------
__global__ __launch_bounds__(256) void convert_bf16(
    const float* __restrict__ in, unsigned short* __restrict__ out, long n8) {
  long i = (long)blockIdx.x * 256 + threadIdx.x;
  if (i >= n8) return;
  float4 a = ((const float4*)in)[i * 2];
  float4 b = ((const float4*)in)[i * 2 + 1];
  union { uint4 u; __hip_bfloat16 h[8]; } pk;
  pk.h[0] = __float2bfloat16(a.x); pk.h[1] = __float2bfloat16(a.y);
  pk.h[2] = __float2bfloat16(a.z); pk.h[3] = __float2bfloat16(a.w);
  pk.h[4] = __float2bfloat16(b.x); pk.h[5] = __float2bfloat16(b.y);
  pk.h[6] = __float2bfloat16(b.z); pk.h[7] = __float2bfloat16(b.w);
  ((uint4*)out)[i] = pk.u;
}

// in[R][C] f32 -> out[C][R] bf16; R,C multiples of 32. grid (C/32, R/32)
__global__ __launch_bounds__(256) void transpose_bf16(
    const float* __restrict__ in, unsigned short* __restrict__ out, int R, int C) {
  __shared__ float t[32][33];
  const int c0 = blockIdx.x * 32, r0 = blockIdx.y * 32;
  const int x = threadIdx.x & 31, y = threadIdx.x >> 5;
  #pragma unroll
  for (int i = y; i < 32; i += 8) t[i][x] = in[(long)(r0 + i) * C + c0 + x];
  __syncthreads();
  #pragma unroll
  for (int i = y; i < 32; i += 8) {
    __hip_bfloat16 v = __float2bfloat16(t[x][i]);
    out[(long)(c0 + i) * R + r0 + x] = *(unsigned short*)&v;
  }
}

// ---------------------------------------------------------------------------
// bf16 MFMA GEMM: C[M,N] = A[M,K] @ Bt[N,K]^T.
// AMODE: 0 plain rows, 1 gather ::2,::2 rows. EPI: 0 f32 store, 1 BN->bf16.
// 256 thr = 4 waves (2x2 of 64x64); BK=64; global_load_lds w=16, source
// pre-swizzled byte^=((row&7)<<4); frag ds_read_b128 with matching XOR.
// Swapped-operand MFMA: lane holds C[m=cl][n=kg*4+r] -> 8B packed stores.
// ---------------------------------------------------------------------------
template<int AMODE, int EPI>
__global__ __launch_bounds__(256) void gemm_mfma(
    const unsigned short* __restrict__ A, const unsigned short* __restrict__ Bt,
    void* __restrict__ Cout, const float* __restrict__ ea, const float* __restrict__ eb,
    int N, int K) {
  __shared__ __align__(16) char As[16384];
  __shared__ __align__(16) char Bs[16384];
  const int tid = threadIdx.x;
  const int lane = tid & 63;
  const int wv = tid >> 6;
  const int wm = (wv >> 1) * 64, wn = (wv & 1) * 64;
  const int m0 = blockIdx.y * 128, n0 = blockIdx.x * 128;
  const int cl = lane & 15, kg = lane >> 4;

  // staging map: srow 0..31 within 32-row group, 8 lanes x 16B per row
  const int srow = tid >> 3;
  const int scolb = (tid & 7) * 16;
  const int swz = scolb ^ ((srow & 7) << 4);   // swizzled source byte col
  const int ldsb = wv * 1024;                  // wave-uniform lds base (per issue)

  long arow[4], brow[4];
  #pragma unroll
  for (int is = 0; is < 4; ++is) {
    int gm = m0 + is * 32 + srow;
    long grow;
    if constexpr (AMODE == 1) {
      int bb = gm / 196, t = gm - bb * 196;
      int h2 = t / 14, w2 = t - h2 * 14;
      grow = (long)(bb * 784 + h2 * 56 + w2 * 2);
    } else {
      grow = gm;
    }
    arow[is] = grow * (long)K;
    brow[is] = (long)(n0 + is * 32 + srow) * (long)K;
  }

  f32x4 acc[4][4];
  const f32x4 zf = {0.f, 0.f, 0.f, 0.f};
  #pragma unroll
  for (int i = 0; i < 4; ++i)
    #pragma unroll
    for (int j = 0; j < 4; ++j) acc[i][j] = zf;

  for (int k0 = 0; k0 < K; k0 += 64) {
    #pragma unroll
    for (int is = 0; is < 4; ++is) {
      gload_lds16((const char*)A  + (arow[is] + k0) * 2 + swz, As + is * 4096 + ldsb);
      gload_lds16((const char*)Bt + (brow[is] + k0) * 2 + swz, Bs + is * 4096 + ldsb);
    }
    __syncthreads();
    bf16x8 afr[4][2], bfr[4][2];
    #pragma unroll
    for (int t = 0; t < 4; ++t) {
      const int ar = wm + t * 16 + cl;
      const int br = wn + t * 16 + cl;
      const int sa = (ar & 7) << 4, sb = (br & 7) << 4;
      afr[t][0] = *(const bf16x8*)(As + ar * 128 + ((kg * 16) ^ sa));
      afr[t][1] = *(const bf16x8*)(As + ar * 128 + ((64 + kg * 16) ^ sa));
      bfr[t][0] = *(const bf16x8*)(Bs + br * 128 + ((kg * 16) ^ sb));
      bfr[t][1] = *(const bf16x8*)(Bs + br * 128 + ((64 + kg * 16) ^ sb));
    }
    #pragma unroll
    for (int mt = 0; mt < 4; ++mt)
      #pragma unroll
      for (int nt = 0; nt < 4; ++nt) {
        acc[mt][nt] = mfma16(bfr[nt][0], afr[mt][0], acc[mt][nt]);
        acc[mt][nt] = mfma16(bfr[nt][1], afr[mt][1], acc[mt][nt]);
      }
    __syncthreads();
  }

  #pragma unroll
  for (int mt = 0; mt < 4; ++mt) {
    const int gm = m0 + wm + mt * 16 + cl;
    #pragma unroll
    for (int nt = 0; nt < 4; ++nt) {
      const int gn = n0 + wn + nt * 16 + kg * 4;
      if constexpr (EPI == 1) {
        float4 a4 = *(const float4*)(ea + gn);
        float4 b4 = *(const float4*)(eb + gn);
        union { ushort4 u; __hip_bfloat16 h[4]; } pk;
        pk.h[0] = __float2bfloat16(acc[mt][nt][0] * a4.x + b4.x);
        pk.h[1] = __float2bfloat16(acc[mt][nt][1] * a4.y + b4.y);
        pk.h[2] = __float2bfloat16(acc[mt][nt][2] * a4.z + b4.z);
        pk.h[3] = __float2bfloat16(acc[mt][nt][3] * a4.w + b4.w);
        *(ushort4*)((unsigned short*)Cout + (long)gm * N + gn) = pk.u;
      } else {
        *(float4*)((float*)Cout + (long)gm * N + gn) =
            make_float4(acc[mt][nt][0], acc[mt][nt][1], acc[mt][nt][2], acc[mt][nt][3]);
      }
    }
  }
}

// ---------------------------------------------------------------------------
// MFMA flash attention (round-2 structure) + hswish fused into the epilogue.
// ---------------------------------------------------------------------------
__global__ __launch_bounds__(512) void attn_mfma(
    const __hip_bfloat16* __restrict__ kv, const __hip_bfloat16* __restrict__ qn,
    const float* __restrict__ bias, __hip_bfloat16* __restrict__ O) {
  const int qt = blockIdx.x, h = blockIdx.y, b = blockIdx.z;
  const int tid = threadIdx.x;
  const int w = tid >> 6;
  const int lane = tid & 63;
  const int cl = lane & 15;
  const int kg = lane >> 4;
  const int kb = kg * 8;
  const int qbase = qt * 112;
  const int valid = 196 - qbase > 112 ? 112 : 196 - qbase;

  __shared__ __align__(16) short Qs[112][72];
  __shared__ __align__(16) short KVs[256][72];
  __shared__ __align__(16) short pPs[112][72];
  __shared__ float marr[112], lsum[112];
  __shared__ float pred[8][112];

  const bf16x8 zero8 = {0,0,0,0,0,0,0,0};
  const f32x4 zerof = {0.f,0.f,0.f,0.f};

  for (int f = tid; f < 896; f += 512) {
    int row = f >> 3, d8 = f & 7;
    bf16x8 v = zero8;
    if (row < valid) {
      v = *(const bf16x8*)(qn + (long)(b * 196 + qbase + row) * 768 + h * 64 + d8 * 8);
    }
    *(bf16x8*)&Qs[row][d8 * 8] = v;
  }
  if (tid < 112) { marr[tid] = -1e30f; lsum[tid] = 0.f; }
  __syncthreads();

  const int mt0 = w >> 2, snt = w & 3;

  // pass 1: row max
  for (int kt = 0; kt < 13; ++kt) {
    const int k0 = kt * 64;
    {
      int kk = tid >> 3, d8 = tid & 7;
      bf16x8 v = zero8;
      if (k0 + kk < 784) {
        v = *(const bf16x8*)(kv + (long)(b * 784 + k0 + kk) * 3840 + h * 64 + d8 * 8);
      }
      *(bf16x8*)&KVs[kk][d8 * 8] = v;
    }
    __syncthreads();
    #pragma unroll
    for (int i = 0; i < 4; ++i) {
      int mt = mt0 + 2 * i;
      if (mt >= 7) break;
      bf16x8 a0 = *(const bf16x8*)&Qs[mt * 16 + cl][kb];
      bf16x8 a1 = *(const bf16x8*)&Qs[mt * 16 + cl][32 + kb];
      bf16x8 b0 = *(const bf16x8*)&KVs[snt * 16 + cl][kb];
      bf16x8 b1 = *(const bf16x8*)&KVs[snt * 16 + cl][32 + kb];
      f32x4 s = mfma16(a1, b1, mfma16(a0, b0, zerof));
      #pragma unroll
      for (int r = 0; r < 4; ++r) {
        float v = s[r] * 0.125f;
        v = fmaxf(v, __shfl_xor(v, 1));
        v = fmaxf(v, __shfl_xor(v, 2));
        v = fmaxf(v, __shfl_xor(v, 4));
        v = fmaxf(v, __shfl_xor(v, 8));
        if (cl == 0) pred[w][mt * 16 + kg * 4 + r] = v;
      }
    }
    __syncthreads();
    if (tid < 112) {
      int wb = ((tid >> 4) & 1) * 4;
      float m = fmaxf(fmaxf(pred[wb][tid], pred[wb + 1][tid]),
                      fmaxf(pred[wb + 2][tid], pred[wb + 3][tid]));
      marr[tid] = fmaxf(marr[tid], m);
    }
  }

  // pass 2
  f32x4 acc[7][2];
  #pragma unroll
  for (int mt = 0; mt < 7; ++mt) { acc[mt][0] = zerof; acc[mt][1] = zerof; }

  for (int kt = 0; kt < 13; ++kt) {
    const int k0 = kt * 64;
    __syncthreads();
    {
      int kk = tid >> 3, d8 = tid & 7;
      bf16x8 v = zero8;
      if (k0 + kk < 784) {
        v = *(const bf16x8*)(kv + (long)(b * 784 + k0 + kk) * 3840 + h * 64 + d8 * 8);
      }
      *(bf16x8*)&KVs[kk][d8 * 8] = v;
    }
    __syncthreads();
    #pragma unroll
    for (int i = 0; i < 4; ++i) {
      int mt = mt0 + 2 * i;
      if (mt >= 7) break;
      bf16x8 a0 = *(const bf16x8*)&Qs[mt * 16 + cl][kb];
      bf16x8 a1 = *(const bf16x8*)&Qs[mt * 16 + cl][32 + kb];
      bf16x8 b0 = *(const bf16x8*)&KVs[snt * 16 + cl][kb];
      bf16x8 b1 = *(const bf16x8*)&KVs[snt * 16 + cl][32 + kb];
      f32x4 s = mfma16(a1, b1, mfma16(a0, b0, zerof));
      int key = k0 + snt * 16 + cl;
      #pragma unroll
      for (int r = 0; r < 4; ++r) {
        int rl = mt * 16 + kg * 4 + r;
        int qrow = qbase + rl;
        bool ok = (qrow < 196) && (key < 784);
        float bb = ok ? bias[(long)qrow * 784 + key] : 0.f;
        float p = ok ? __expf(s[r] * 0.125f + bb - marr[rl]) : 0.f;
        float ps = p;
        ps += __shfl_xor(ps, 1);
        ps += __shfl_xor(ps, 2);
        ps += __shfl_xor(ps, 4);
        ps += __shfl_xor(ps, 8);
        if (cl == 0) pred[w][rl] = ps;
        __hip_bfloat16 pb = __float2bfloat16(p);
        pPs[rl][snt * 16 + cl] = *(short*)&pb;
      }
    }
    __syncthreads();
    #pragma unroll
    for (int l = 0; l < 4; ++l) {
      int f = tid + l * 512;
      int dv8 = f & 31, kk = f >> 5;
      union { uint4 u; short s[8]; } vv;
      if (k0 + kk < 784) {
        vv.u = *(const uint4*)(kv + (long)(b * 784 + k0 + kk) * 3840 + 768 + h * 256 + dv8 * 8);
      } else {
        vv.u = make_uint4(0, 0, 0, 0);
      }
      int col = (((kk >> 3) ^ (dv8 & 7)) << 3) | (kk & 7);
      #pragma unroll
      for (int j = 0; j < 8; ++j) KVs[dv8 * 8 + j][col] = vv.s[j];
    }
    __syncthreads();
    if (tid < 112) {
      int wb = ((tid >> 4) & 1) * 4;
      lsum[tid] += pred[wb][tid] + pred[wb + 1][tid] + pred[wb + 2][tid] + pred[wb + 3][tid];
    }
    #pragma unroll
    for (int mt = 0; mt < 7; ++mt) {
      #pragma unroll
      for (int kc = 0; kc < 2; ++kc) {
        bf16x8 a = *(const bf16x8*)&pPs[mt * 16 + cl][kc * 32 + kb];
        int g = kc * 4 + kg;
        #pragma unroll
        for (int nt2 = 0; nt2 < 2; ++nt2) {
          int dv = w * 32 + nt2 * 16 + cl;
          bf16x8 bv = *(const bf16x8*)&KVs[dv][(g ^ ((dv >> 3) & 7)) << 3];
          acc[mt][nt2] = mfma16(a, bv, acc[mt][nt2]);
        }
      }
    }
  }
  __syncthreads();

  #pragma unroll
  for (int mt = 0; mt < 7; ++mt) {
    #pragma unroll
    for (int r = 0; r < 4; ++r) {
      int rl = mt * 16 + kg * 4 + r;
      if (rl < valid) {
        float li = 1.0f / lsum[rl];
        #pragma unroll
        for (int nt2 = 0; nt2 < 2; ++nt2) {
          float ov = acc[mt][nt2][r] * li;
          O[(long)(b * 196 + qbase + rl) * 3072 + h * 256 + w * 32 + nt2 * 16 + cl] =
              __float2bfloat16(hswish(ov));
        }
      }
    }
  }
}

// ---------------------------------------------------------------------------
extern "C" void kernel_launch(void* const* d_in, const int* in_sizes, int n_in,
                              void* d_out, int out_size, void* d_ws, size_t ws_size,
                              hipStream_t stream) {
  if (ws_size < WS_TOTAL) return;

  const float* x    = (const float*)d_in[0];
  const float* Wqkv = (const float*)d_in[1];
  const float* bn1s = (const float*)d_in[2];
  const float* Wq   = (const float*)d_in[3];
  const float* bn2s = (const float*)d_in[4];
  const float* bias = (const float*)d_in[5];
  const float* Wout = (const float*)d_in[6];

  char* ws = (char*)d_ws;
  unsigned short* kvb  = (unsigned short*)(ws + OFF_KV);
  unsigned short* qnb  = (unsigned short*)(ws + OFF_QN);
  unsigned short* xb   = (unsigned short*)(ws + OFF_XB);
  unsigned short* Ob   = (unsigned short*)(ws + OFF_O);
  unsigned short* wqkvt= (unsigned short*)(ws + OFF_WQKVT);
  unsigned short* wqt  = (unsigned short*)(ws + OFF_WQT);
  unsigned short* woutt= (unsigned short*)(ws + OFF_WOUTT);
  float* ps1  = (float*)(ws + OFF_PS1);
  float* pcs1 = (float*)(ws + OFF_PCS1);
  float* ps2  = (float*)(ws + OFF_PS2);
  float* pcs2 = (float*)(ws + OFF_PCS2);
  float* sx1  = (float*)(ws + OFF_SX1);
  float* cs1  = (float*)(ws + OFF_CS1);
  float* sx2  = (float*)(ws + OFF_SX2);
  float* cs2  = (float*)(ws + OFF_CS2);
  float* a1w  = (float*)(ws + OFF_A1);
  float* b1w  = (float*)(ws + OFF_B1);
  float* a2w  = (float*)(ws + OFF_A2);
  float* b2w  = (float*)(ws + OFF_B2);
  float* out  = (float*)d_out;

  // BN stats (f32, exact)
  xtx_partial<0><<<dim3(36, CH1), 256, 0, stream>>>(x, ps1, pcs1, M1 / CH1);
  xtx_partial<1><<<dim3(36, CH2), 256, 0, stream>>>(x, ps2, pcs2, M2 / CH2);
  reduce_chunks<<<dim3(576), 256, 0, stream>>>(ps1, sx1, 384 * 384, CH1);
  reduce_chunks<<<dim3(2),   256, 0, stream>>>(pcs1, cs1, 384, CH1);
  reduce_chunks<<<dim3(576), 256, 0, stream>>>(ps2, sx2, 384 * 384, CH2);
  reduce_chunks<<<dim3(2),   256, 0, stream>>>(pcs2, cs2, 384, CH2);
  bnprep<<<dim3(3840), 256, 0, stream>>>(Wqkv, sx1, cs1, bn1s, a1w, b1w, N1, 1.f / (float)M1);
  bnprep<<<dim3(768),  256, 0, stream>>>(Wq,   sx2, cs2, bn2s, a2w, b2w, Dq, 1.f / (float)M2);

  // prep bf16 operands (PS1 region is dead after the reduces)
  convert_bf16<<<dim3(4704), 256, 0, stream>>>(x, xb, (long)M1 * Kc / 8);
  transpose_bf16<<<dim3(120, 12), 256, 0, stream>>>(Wqkv, wqkvt, Kc, N1);
  transpose_bf16<<<dim3(24, 12),  256, 0, stream>>>(Wq,   wqt,   Kc, Dq);
  transpose_bf16<<<dim3(16, 96),  256, 0, stream>>>(Wout, woutt, 4 * Dq, OUTD);

  // KV = BN(xb @ Wqkvt^T) -> bf16
  gemm_mfma<0, 1><<<dim3(30, 196), 256, 0, stream>>>(xb, wqkvt, kvb, a1w, b1w, N1, Kc);
  // Qn = BN(xb[::2,::2] @ wqt^T) -> bf16
  gemm_mfma<1, 1><<<dim3(6, 49), 256, 0, stream>>>(xb, wqt, qnb, a2w, b2w, Dq, Kc);
  // attention -> hswish(O) bf16  (overwrites xb region; xb is dead)
  attn_mfma<<<dim3(2, 12, 32), 512, 0, stream>>>(
      (const __hip_bfloat16*)kvb, (const __hip_bfloat16*)qnb, bias, (__hip_bfloat16*)Ob);
  // out = hswishO @ woutt^T -> f32
  gemm_mfma<0, 0><<<dim3(4, 49), 256, 0, stream>>>(Ob, woutt, out, nullptr, nullptr, OUTD, 4 * Dq);
}

// Round 5
// 850.342 us; speedup vs baseline: 7.8115x; 1.4251x over previous
//
#include <hip/hip_runtime.h>
#include <hip/hip_bf16.h>

// ---------------------------------------------------------------------------
// LeViT subsample attention (round 4).
//   1. Sx = x^T x (+colsum) -> analytic BN coefficients (f32)
//   2. prep: x -> bf16; weights -> transposed bf16 [N][K]
//   3. gemm_mfma<EPI=1>: Kbuf = BN(x @ Wk) row-major bf16 [25088][768]
//      gemm_mfma<EPI=2>: Vt   = BN(x @ Wv) TRANSPOSED bf16 [b][h][dv][784]
//      gemm_mfma<EPI=1>: Qn (gathered rows)
//   4. attn_mfma: single-pass, no-max softmax; swapped QK^T (lane owns 4 keys),
//      V fragments from global Vt (no V LDS); hswish fused -> O bf16
//   5. gemm_mfma<EPI=0>: out = O @ Wout^T -> f32
// ---------------------------------------------------------------------------

static constexpr int M1 = 25088, N1 = 3840, Kc = 384;
static constexpr int M2 = 6272, Dq = 768, OUTD = 512;
static constexpr int CH1 = 14, CH2 = 7;

static constexpr size_t OFF_K    = 0;            // bf16 25088x768
static constexpr size_t OFF_VT   = 38535168;     // bf16 (32*12*256)x784
static constexpr size_t OFF_QN   = 192675840;    // bf16 6272x768
static constexpr size_t OFF_O    = 202309632;    // bf16 6272x3072 (x_bf16 early)
static constexpr size_t OFF_XB   = OFF_O;
static constexpr size_t OFF_PS1  = 240844800;    // f32 14x384x384 (dead after reduce)
static constexpr size_t OFF_WQKVT= 240844800;    // bf16 3840x384 (over PS1)
static constexpr size_t OFF_WQT  = 243793920;    // bf16 768x384
static constexpr size_t OFF_WOUTT= 244383744;    // bf16 512x3072
static constexpr size_t OFF_PCS1 = 249102336;
static constexpr size_t OFF_PS2  = 249123840;
static constexpr size_t OFF_PCS2 = 253252608;
static constexpr size_t OFF_SX1  = 253263360;
static constexpr size_t OFF_CS1  = 253853184;
static constexpr size_t OFF_SX2  = 253854720;
static constexpr size_t OFF_CS2  = 254444544;
static constexpr size_t OFF_A1   = 254446080;
static constexpr size_t OFF_B1   = 254461440;
static constexpr size_t OFF_A2   = 254476800;
static constexpr size_t OFF_B2   = 254479872;
static constexpr size_t WS_TOTAL = 254482944;

typedef __attribute__((ext_vector_type(8))) short bf16x8;
typedef __attribute__((ext_vector_type(4))) float f32x4;

static __device__ __forceinline__ f32x4 mfma16(bf16x8 a, bf16x8 b, f32x4 c) {
  return __builtin_amdgcn_mfma_f32_16x16x32_bf16(a, b, c, 0, 0, 0);
}

__device__ __forceinline__ void gload_lds16(const void* g, void* l) {
  __builtin_amdgcn_global_load_lds(
      (const __attribute__((address_space(1))) unsigned int*)g,
      (__attribute__((address_space(3))) unsigned int*)l, 16, 0, 0);
}

__device__ __forceinline__ float hswish(float x) {
  float t = fminf(fmaxf(x + 3.0f, 0.0f), 6.0f);
  return x * t * (1.0f / 6.0f);
}

__device__ __forceinline__ void fma4x4(float (&c)[4][4], const float4 a, const float4 b) {
  c[0][0] += a.x*b.x; c[0][1] += a.x*b.y; c[0][2] += a.x*b.z; c[0][3] += a.x*b.w;
  c[1][0] += a.y*b.x; c[1][1] += a.y*b.y; c[1][2] += a.y*b.z; c[1][3] += a.y*b.w;
  c[2][0] += a.z*b.x; c[2][1] += a.z*b.y; c[2][2] += a.z*b.z; c[2][3] += a.z*b.w;
  c[3][0] += a.w*b.x; c[3][1] += a.w*b.y; c[3][2] += a.w*b.z; c[3][3] += a.w*b.w;
}

// --------------------------- X^T X partials (f32) --------------------------
template<int GATHER>
__global__ __launch_bounds__(256) void xtx_partial(
    const float* __restrict__ X, float* __restrict__ pS, float* __restrict__ pcs,
    int rows_per_chunk) {
  const int ti = blockIdx.x / 6, tj = blockIdx.x % 6;
  const int chunk = blockIdx.y;
  const int tid = threadIdx.x;
  const int tx = tid & 15, ty = tid >> 4;
  __shared__ __align__(16) float xa[32][64];
  __shared__ __align__(16) float xb[32][64];
  __shared__ float redcs[256];
  float acc[4][4] = {};
  float cs = 0.f;
  const int cq = tid & 63, rq = tid >> 6;

  for (int rr = 0; rr < rows_per_chunk; rr += 32) {
    #pragma unroll
    for (int l = 0; l < 2; ++l) {
      int f = tid + l * 256;
      int r = f >> 4, c4 = f & 15;
      int m = chunk * rows_per_chunk + rr + r;
      long grow;
      if constexpr (GATHER) {
        int bb = m / 196, t = m - bb * 196;
        int h2 = t / 14, w2 = t - h2 * 14;
        grow = (long)(bb * 784 + h2 * 56 + w2 * 2);
      } else {
        grow = m;
      }
      const float* src = X + grow * 384;
      *(float4*)&xa[r][c4 * 4] = *(const float4*)(src + ti * 64 + c4 * 4);
      *(float4*)&xb[r][c4 * 4] = *(const float4*)(src + tj * 64 + c4 * 4);
    }
    __syncthreads();
    if (ti == 0) {
      #pragma unroll
      for (int r = 0; r < 8; ++r) cs += xb[rq * 8 + r][cq];
    }
    #pragma unroll
    for (int r = 0; r < 32; ++r) {
      float4 av = *(const float4*)&xa[r][ty * 4];
      float4 bv = *(const float4*)&xb[r][tx * 4];
      fma4x4(acc, av, bv);
    }
    __syncthreads();
  }
  #pragma unroll
  for (int r = 0; r < 4; ++r) {
    *(float4*)(pS + ((long)chunk * 384 + ti * 64 + ty * 4 + r) * 384 + tj * 64 + tx * 4) =
        make_float4(acc[r][0], acc[r][1], acc[r][2], acc[r][3]);
  }
  if (ti == 0) {
    redcs[tid] = cs;
    __syncthreads();
    if (tid < 64) {
      pcs[(long)chunk * 384 + tj * 64 + tid] =
          redcs[tid] + redcs[tid + 64] + redcs[tid + 128] + redcs[tid + 192];
    }
  }
}

__global__ __launch_bounds__(256) void reduce_chunks(
    const float* __restrict__ src, float* __restrict__ dst, int nelem, int nchunks) {
  int i = blockIdx.x * 256 + threadIdx.x;
  if (i >= nelem) return;
  float s = 0.f;
  for (int c = 0; c < nchunks; ++c) s += src[(long)c * nelem + i];
  dst[i] = s;
}

__global__ __launch_bounds__(256) void bnprep(
    const float* __restrict__ W, const float* __restrict__ Sx, const float* __restrict__ cs,
    const float* __restrict__ scale, float* __restrict__ a, float* __restrict__ b,
    int N, float invM) {
  const int j = blockIdx.x;
  __shared__ __align__(16) float wj[384];
  __shared__ float red[256], red2[256];
  for (int k = threadIdx.x; k < 384; k += 256) wj[k] = W[(long)k * N + j];
  __syncthreads();
  float yy = 0.f, mu = 0.f;
  for (int k = threadIdx.x; k < 384; k += 256) {
    float rowdot = 0.f;
    const float* srow = Sx + (long)k * 384;
    #pragma unroll 8
    for (int l = 0; l < 384; l += 4) {
      float4 s = *(const float4*)(srow + l);
      float4 w = *(const float4*)(&wj[l]);
      rowdot += s.x*w.x + s.y*w.y + s.z*w.z + s.w*w.w;
    }
    yy += wj[k] * rowdot;
    mu += cs[k] * wj[k];
  }
  red[threadIdx.x] = yy; red2[threadIdx.x] = mu;
  __syncthreads();
  for (int s = 128; s > 0; s >>= 1) {
    if (threadIdx.x < s) { red[threadIdx.x] += red[threadIdx.x + s]; red2[threadIdx.x] += red2[threadIdx.x + s]; }
    __syncthreads();
  }
  if (threadIdx.x == 0) {
    float mean = red2[0] * invM;
    float var = red[0] * invM - mean * mean;
    float ai = rsqrtf(var + 1e-5f) * scale[j];
    a[j] = ai;
    b[j] = -mean * ai;
  }
}

// --------------------------- prep: convert / transpose ---------------------
__global__ __launch_bounds__(256) void convert_bf16(
    const float* __restrict__ in, unsigned short* __restrict__ out, long n8) {
  long i = (long)blockIdx.x * 256 + threadIdx.x;
  if (i >= n8) return;
  float4 a = ((const float4*)in)[i * 2];
  float4 b = ((const float4*)in)[i * 2 + 1];
  union { uint4 u; __hip_bfloat16 h[8]; } pk;
  pk.h[0] = __float2bfloat16(a.x); pk.h[1] = __float2bfloat16(a.y);
  pk.h[2] = __float2bfloat16(a.z); pk.h[3] = __float2bfloat16(a.w);
  pk.h[4] = __float2bfloat16(b.x); pk.h[5] = __float2bfloat16(b.y);
  pk.h[6] = __float2bfloat16(b.z); pk.h[7] = __float2bfloat16(b.w);
  ((uint4*)out)[i] = pk.u;
}

__global__ __launch_bounds__(256) void transpose_bf16(
    const float* __restrict__ in, unsigned short* __restrict__ out, int R, int C) {
  __shared__ float t[32][33];
  const int c0 = blockIdx.x * 32, r0 = blockIdx.y * 32;
  const int x = threadIdx.x & 31, y = threadIdx.x >> 5;
  #pragma unroll
  for (int i = y; i < 32; i += 8) t[i][x] = in[(long)(r0 + i) * C + c0 + x];
  __syncthreads();
  #pragma unroll
  for (int i = y; i < 32; i += 8) {
    __hip_bfloat16 v = __float2bfloat16(t[x][i]);
    out[(long)(c0 + i) * R + r0 + x] = *(unsigned short*)&v;
  }
}

// ---------------------------------------------------------------------------
// bf16 MFMA GEMM: C = A[M,K] @ Bt[N,K]^T.
// AMODE: 0 plain rows, 1 gather ::2,::2 rows.
// EPI: 0 f32 row store; 1 BN->bf16 row store (swapped mfma, packed N);
//      2 BN->bf16 TRANSPOSED store into Vt[b][h][dv][784] (unswapped mfma).
// ---------------------------------------------------------------------------
template<int AMODE, int EPI>
__global__ __launch_bounds__(256) void gemm_mfma(
    const unsigned short* __restrict__ A, const unsigned short* __restrict__ Bt,
    void* __restrict__ Cout, const float* __restrict__ ea, const float* __restrict__ eb,
    int N, int K) {
  __shared__ __align__(16) char As[16384];
  __shared__ __align__(16) char Bs[16384];
  const int tid = threadIdx.x;
  const int lane = tid & 63;
  const int wv = tid >> 6;
  const int wm = (wv >> 1) * 64, wn = (wv & 1) * 64;
  const int m0 = blockIdx.y * 128, n0 = blockIdx.x * 128;
  const int cl = lane & 15, kg = lane >> 4;

  const int srow = tid >> 3;
  const int scolb = (tid & 7) * 16;
  const int swz = scolb ^ ((srow & 7) << 4);
  const int ldsb = wv * 1024;

  long arow[4], brow[4];
  #pragma unroll
  for (int is = 0; is < 4; ++is) {
    int gm = m0 + is * 32 + srow;
    long grow;
    if constexpr (AMODE == 1) {
      int bb = gm / 196, t = gm - bb * 196;
      int h2 = t / 14, w2 = t - h2 * 14;
      grow = (long)(bb * 784 + h2 * 56 + w2 * 2);
    } else {
      grow = gm;
    }
    arow[is] = grow * (long)K;
    brow[is] = (long)(n0 + is * 32 + srow) * (long)K;
  }

  f32x4 acc[4][4];
  const f32x4 zf = {0.f, 0.f, 0.f, 0.f};
  #pragma unroll
  for (int i = 0; i < 4; ++i)
    #pragma unroll
    for (int j = 0; j < 4; ++j) acc[i][j] = zf;

  for (int k0 = 0; k0 < K; k0 += 64) {
    #pragma unroll
    for (int is = 0; is < 4; ++is) {
      gload_lds16((const char*)A  + (arow[is] + k0) * 2 + swz, As + is * 4096 + ldsb);
      gload_lds16((const char*)Bt + (brow[is] + k0) * 2 + swz, Bs + is * 4096 + ldsb);
    }
    __syncthreads();
    bf16x8 afr[4][2], bfr[4][2];
    #pragma unroll
    for (int t = 0; t < 4; ++t) {
      const int ar = wm + t * 16 + cl;
      const int br = wn + t * 16 + cl;
      const int sa = (ar & 7) << 4, sb = (br & 7) << 4;
      afr[t][0] = *(const bf16x8*)(As + ar * 128 + ((kg * 16) ^ sa));
      afr[t][1] = *(const bf16x8*)(As + ar * 128 + ((64 + kg * 16) ^ sa));
      bfr[t][0] = *(const bf16x8*)(Bs + br * 128 + ((kg * 16) ^ sb));
      bfr[t][1] = *(const bf16x8*)(Bs + br * 128 + ((64 + kg * 16) ^ sb));
    }
    #pragma unroll
    for (int mt = 0; mt < 4; ++mt)
      #pragma unroll
      for (int nt = 0; nt < 4; ++nt) {
        if constexpr (EPI == 2) {
          acc[mt][nt] = mfma16(afr[mt][0], bfr[nt][0], acc[mt][nt]);
          acc[mt][nt] = mfma16(afr[mt][1], bfr[nt][1], acc[mt][nt]);
        } else {
          acc[mt][nt] = mfma16(bfr[nt][0], afr[mt][0], acc[mt][nt]);
          acc[mt][nt] = mfma16(bfr[nt][1], afr[mt][1], acc[mt][nt]);
        }
      }
    __syncthreads();
  }

  #pragma unroll
  for (int mt = 0; mt < 4; ++mt) {
    #pragma unroll
    for (int nt = 0; nt < 4; ++nt) {
      if constexpr (EPI == 2) {
        // lane: rows (k) = gm0..gm0+3, col (dv) = gn
        const int gm0 = m0 + wm + mt * 16 + kg * 4;
        const int gn = n0 + wn + nt * 16 + cl;       // 0..3071 within V
        const int bb = gm0 / 784, kk = gm0 - bb * 784;
        const int hh = gn >> 8, dvl = gn & 255;
        const float av = ea[gn], bv = eb[gn];
        union { ushort4 u; __hip_bfloat16 h[4]; } pk;
        pk.h[0] = __float2bfloat16(acc[mt][nt][0] * av + bv);
        pk.h[1] = __float2bfloat16(acc[mt][nt][1] * av + bv);
        pk.h[2] = __float2bfloat16(acc[mt][nt][2] * av + bv);
        pk.h[3] = __float2bfloat16(acc[mt][nt][3] * av + bv);
        *(ushort4*)((unsigned short*)Cout +
                    ((long)(bb * 12 + hh) * 256 + dvl) * 784 + kk) = pk.u;
      } else {
        const int gm = m0 + wm + mt * 16 + cl;
        const int gn = n0 + wn + nt * 16 + kg * 4;
        if constexpr (EPI == 1) {
          float4 a4 = *(const float4*)(ea + gn);
          float4 b4 = *(const float4*)(eb + gn);
          union { ushort4 u; __hip_bfloat16 h[4]; } pk;
          pk.h[0] = __float2bfloat16(acc[mt][nt][0] * a4.x + b4.x);
          pk.h[1] = __float2bfloat16(acc[mt][nt][1] * a4.y + b4.y);
          pk.h[2] = __float2bfloat16(acc[mt][nt][2] * a4.z + b4.z);
          pk.h[3] = __float2bfloat16(acc[mt][nt][3] * a4.w + b4.w);
          *(ushort4*)((unsigned short*)Cout + (long)gm * N + gn) = pk.u;
        } else {
          *(float4*)((float*)Cout + (long)gm * N + gn) =
              make_float4(acc[mt][nt][0], acc[mt][nt][1], acc[mt][nt][2], acc[mt][nt][3]);
        }
      }
    }
  }
}

// ---------------------------------------------------------------------------
// Single-pass MFMA flash attention, no max subtraction (scores bounded).
// Block = (qt 112 rows, h, b), 512 thr = 8 waves. Wave w: snt=w&3 (16-key
// column group), mt parity w>>2; PV dv-slice w*32.
// Swapped QK^T: lane holds S[key quad][q] -> float4 bias, packed P write.
// V fragments straight from global Vt into registers (4 x b128 per tile).
// ---------------------------------------------------------------------------
__global__ __launch_bounds__(512, 4) void attn_mfma(
    const unsigned short* __restrict__ kbuf, const unsigned short* __restrict__ vt,
    const unsigned short* __restrict__ qn, const float* __restrict__ bias,
    unsigned short* __restrict__ O) {
  const int qt = blockIdx.x, h = blockIdx.y, b = blockIdx.z;
  const int tid = threadIdx.x;
  const int w = tid >> 6;
  const int lane = tid & 63;
  const int cl = lane & 15;
  const int kg = lane >> 4;
  const int qbase = qt * 112;
  const int valid = 196 - qbase > 112 ? 112 : 196 - qbase;
  const int bh = b * 12 + h;

  __shared__ __align__(16) short Qs[112][72];
  __shared__ __align__(16) short Ks[2][64][72];
  __shared__ __align__(16) short pPs[112][72];
  __shared__ float pred[4][112];
  __shared__ float lsum[112];

  const bf16x8 zero8 = {0,0,0,0,0,0,0,0};
  const f32x4 zerof = {0.f,0.f,0.f,0.f};

  // stage Q (invalid rows zero)
  for (int f = tid; f < 896; f += 512) {
    int row = f >> 3, d8 = f & 7;
    bf16x8 v = zero8;
    if (row < valid)
      v = *(const bf16x8*)(qn + (long)(b * 196 + qbase + row) * 768 + h * 64 + d8 * 8);
    *(bf16x8*)&Qs[row][d8 * 8] = v;
  }
  // stage K tile 0
  {
    int kk = tid >> 3, d8 = tid & 7;
    bf16x8 v = *(const bf16x8*)(kbuf + ((long)b * 784 + kk) * 768 + h * 64 + d8 * 8);
    *(bf16x8*)&Ks[0][kk][d8 * 8] = v;
  }
  __syncthreads();

  const int mt0 = w >> 2, snt = w & 3;
  const int kb = kg * 8;

  f32x4 acc[7][2];
  #pragma unroll
  for (int mt = 0; mt < 7; ++mt) { acc[mt][0] = zerof; acc[mt][1] = zerof; }
  float lpart[4] = {0.f, 0.f, 0.f, 0.f};

  for (int kt = 0; kt < 13; ++kt) {
    const int k0 = kt * 64;
    const int cur = kt & 1;
    // prefetch next K tile into the other buffer
    if (kt < 12) {
      int kk = tid >> 3, d8 = tid & 7;
      bf16x8 v = zero8;
      if (k0 + 64 + kk < 784)
        v = *(const bf16x8*)(kbuf + ((long)b * 784 + k0 + 64 + kk) * 768 + h * 64 + d8 * 8);
      *(bf16x8*)&Ks[cur ^ 1][kk][d8 * 8] = v;
    }
    // V fragments for this tile: global -> regs
    bf16x8 vf00, vf01, vf10, vf11;
    {
      const long vrow0 = ((long)bh * 256 + w * 32 + cl) * 784;
      const long vrow1 = ((long)bh * 256 + w * 32 + 16 + cl) * 784;
      vf00 = *(const bf16x8*)(vt + vrow0 + k0 + kb);
      vf10 = *(const bf16x8*)(vt + vrow0 + k0 + 32 + kb);
      vf01 = *(const bf16x8*)(vt + vrow1 + k0 + kb);
      vf11 = *(const bf16x8*)(vt + vrow1 + k0 + 32 + kb);
    }
    // scores -> P (bf16, packed write), lsum partials in regs
    #pragma unroll
    for (int i = 0; i < 4; ++i) {
      int mt = mt0 + 2 * i;
      if (mt >= 7) break;
      bf16x8 q0 = *(const bf16x8*)&Qs[mt * 16 + cl][kb];
      bf16x8 q1 = *(const bf16x8*)&Qs[mt * 16 + cl][32 + kb];
      bf16x8 kk0 = *(const bf16x8*)&Ks[cur][snt * 16 + cl][kb];
      bf16x8 kk1 = *(const bf16x8*)&Ks[cur][snt * 16 + cl][32 + kb];
      f32x4 s = mfma16(kk1, q1, mfma16(kk0, q0, zerof));
      // lane: q row = mt*16+cl, keys = k0 + snt*16 + kg*4 + r
      const int rowl = mt * 16 + cl;
      const int key0 = k0 + snt * 16 + kg * 4;
      const bool ok = (rowl < valid) && (key0 < 784);
      float4 b4 = make_float4(0.f, 0.f, 0.f, 0.f);
      if (ok) b4 = *(const float4*)(bias + (long)(qbase + rowl) * 784 + key0);
      float p0 = ok ? __expf(s[0] * 0.125f + b4.x) : 0.f;
      float p1 = ok ? __expf(s[1] * 0.125f + b4.y) : 0.f;
      float p2 = ok ? __expf(s[2] * 0.125f + b4.z) : 0.f;
      float p3 = ok ? __expf(s[3] * 0.125f + b4.w) : 0.f;
      lpart[i] += (p0 + p1) + (p2 + p3);
      union { ushort4 u; __hip_bfloat16 hh[4]; } pk;
      pk.hh[0] = __float2bfloat16(p0);
      pk.hh[1] = __float2bfloat16(p1);
      pk.hh[2] = __float2bfloat16(p2);
      pk.hh[3] = __float2bfloat16(p3);
      *(ushort4*)&pPs[rowl][snt * 16 + kg * 4] = pk.u;
    }
    __syncthreads();
    // PV: wave w owns dv slice [w*32, w*32+32)
    #pragma unroll
    for (int mt = 0; mt < 7; ++mt) {
      bf16x8 pa0 = *(const bf16x8*)&pPs[mt * 16 + cl][kb];
      bf16x8 pa1 = *(const bf16x8*)&pPs[mt * 16 + cl][32 + kb];
      acc[mt][0] = mfma16(pa0, vf00, acc[mt][0]);
      acc[mt][0] = mfma16(pa1, vf10, acc[mt][0]);
      acc[mt][1] = mfma16(pa0, vf01, acc[mt][1]);
      acc[mt][1] = mfma16(pa1, vf11, acc[mt][1]);
    }
    __syncthreads();
  }

  // lsum: reduce lane partials over kg, then across the 4 snt waves
  #pragma unroll
  for (int i = 0; i < 4; ++i) {
    int mt = mt0 + 2 * i;
    if (mt >= 7) break;
    float v = lpart[i];
    v += __shfl_xor(v, 16);
    v += __shfl_xor(v, 32);
    if (kg == 0) pred[snt][mt * 16 + cl] = v;
  }
  __syncthreads();
  if (tid < 112)
    lsum[tid] = (pred[0][tid] + pred[1][tid]) + (pred[2][tid] + pred[3][tid]);
  __syncthreads();

  // store O = hswish(acc / lsum)
  #pragma unroll
  for (int mt = 0; mt < 7; ++mt) {
    #pragma unroll
    for (int r = 0; r < 4; ++r) {
      const int rl = mt * 16 + kg * 4 + r;
      if (rl < valid) {
        const float inv = 1.0f / lsum[rl];
        #pragma unroll
        for (int nt2 = 0; nt2 < 2; ++nt2) {
          float ov = hswish(acc[mt][nt2][r] * inv);
          __hip_bfloat16 hv = __float2bfloat16(ov);
          O[(long)(b * 196 + qbase + rl) * 3072 + h * 256 + w * 32 + nt2 * 16 + cl] =
              *(unsigned short*)&hv;
        }
      }
    }
  }
}

// ---------------------------------------------------------------------------
extern "C" void kernel_launch(void* const* d_in, const int* in_sizes, int n_in,
                              void* d_out, int out_size, void* d_ws, size_t ws_size,
                              hipStream_t stream) {
  if (ws_size < WS_TOTAL) return;

  const float* x    = (const float*)d_in[0];
  const float* Wqkv = (const float*)d_in[1];
  const float* bn1s = (const float*)d_in[2];
  const float* Wq   = (const float*)d_in[3];
  const float* bn2s = (const float*)d_in[4];
  const float* bias = (const float*)d_in[5];
  const float* Wout = (const float*)d_in[6];

  char* ws = (char*)d_ws;
  unsigned short* kb   = (unsigned short*)(ws + OFF_K);
  unsigned short* vtb  = (unsigned short*)(ws + OFF_VT);
  unsigned short* qnb  = (unsigned short*)(ws + OFF_QN);
  unsigned short* xb   = (unsigned short*)(ws + OFF_XB);
  unsigned short* Ob   = (unsigned short*)(ws + OFF_O);
  unsigned short* wqkvt= (unsigned short*)(ws + OFF_WQKVT);
  unsigned short* wqt  = (unsigned short*)(ws + OFF_WQT);
  unsigned short* woutt= (unsigned short*)(ws + OFF_WOUTT);
  float* ps1  = (float*)(ws + OFF_PS1);
  float* pcs1 = (float*)(ws + OFF_PCS1);
  float* ps2  = (float*)(ws + OFF_PS2);
  float* pcs2 = (float*)(ws + OFF_PCS2);
  float* sx1  = (float*)(ws + OFF_SX1);
  float* cs1  = (float*)(ws + OFF_CS1);
  float* sx2  = (float*)(ws + OFF_SX2);
  float* cs2  = (float*)(ws + OFF_CS2);
  float* a1w  = (float*)(ws + OFF_A1);
  float* b1w  = (float*)(ws + OFF_B1);
  float* a2w  = (float*)(ws + OFF_A2);
  float* b2w  = (float*)(ws + OFF_B2);
  float* out  = (float*)d_out;

  xtx_partial<0><<<dim3(36, CH1), 256, 0, stream>>>(x, ps1, pcs1, M1 / CH1);
  xtx_partial<1><<<dim3(36, CH2), 256, 0, stream>>>(x, ps2, pcs2, M2 / CH2);
  reduce_chunks<<<dim3(576), 256, 0, stream>>>(ps1, sx1, 384 * 384, CH1);
  reduce_chunks<<<dim3(2),   256, 0, stream>>>(pcs1, cs1, 384, CH1);
  reduce_chunks<<<dim3(576), 256, 0, stream>>>(ps2, sx2, 384 * 384, CH2);
  reduce_chunks<<<dim3(2),   256, 0, stream>>>(pcs2, cs2, 384, CH2);
  bnprep<<<dim3(3840), 256, 0, stream>>>(Wqkv, sx1, cs1, bn1s, a1w, b1w, N1, 1.f / (float)M1);
  bnprep<<<dim3(768),  256, 0, stream>>>(Wq,   sx2, cs2, bn2s, a2w, b2w, Dq, 1.f / (float)M2);

  convert_bf16<<<dim3(4704), 256, 0, stream>>>(x, xb, (long)M1 * Kc / 8);
  transpose_bf16<<<dim3(120, 12), 256, 0, stream>>>(Wqkv, wqkvt, Kc, N1);
  transpose_bf16<<<dim3(24, 12),  256, 0, stream>>>(Wq,   wqt,   Kc, Dq);
  transpose_bf16<<<dim3(16, 96),  256, 0, stream>>>(Wout, woutt, 4 * Dq, OUTD);

  // K part: rows 0..767 of W_qkv -> row-major Kbuf
  gemm_mfma<0, 1><<<dim3(6, 196), 256, 0, stream>>>(xb, wqkvt, kb, a1w, b1w, 768, Kc);
  // V part: rows 768..3839 -> transposed Vt
  gemm_mfma<0, 2><<<dim3(24, 196), 256, 0, stream>>>(
      xb, wqkvt + (long)768 * Kc, vtb, a1w + 768, b1w + 768, 3072, Kc);
  // Qn
  gemm_mfma<1, 1><<<dim3(6, 49), 256, 0, stream>>>(xb, wqt, qnb, a2w, b2w, Dq, Kc);
  // attention -> hswish(O)
  attn_mfma<<<dim3(2, 12, 32), 512, 0, stream>>>(kb, vtb, qnb, bias, Ob);
  // out = O @ Wout^T
  gemm_mfma<0, 0><<<dim3(4, 49), 256, 0, stream>>>(Ob, woutt, out, nullptr, nullptr, OUTD, 4 * Dq);
}

// Round 6
// 600.348 us; speedup vs baseline: 11.0644x; 1.4164x over previous
//
#include <hip/hip_runtime.h>
#include <hip/hip_bf16.h>

// ---------------------------------------------------------------------------
// LeViT subsample attention (round 5).
//   1. Sx = x^T x (+colsum) split-K partials (f32)
//   2. prep: x,Sx -> bf16; weights -> transposed bf16 [N][K]
//   3. BN coeffs via GEMM: T = Sx @ W (MFMA) ; bnfinal: yy=sum W.*T, mu=cs.w
//   4. Kbuf = BN(x@Wk) row-major; Vt = BN(x@Wv) transposed; Qn (gathered)
//   5. attn_mfma: single-pass no-max softmax, V from global -> hswish(O)
//   6. out = O @ Wout^T -> f32
// ---------------------------------------------------------------------------

static constexpr int M1 = 25088, N1 = 3840, Kc = 384;
static constexpr int M2 = 6272, Dq = 768, OUTD = 512;
static constexpr int CH1 = 14, CH2 = 7;

static constexpr size_t OFF_K    = 0;            // bf16 25088x768 (late)
static constexpr size_t OFF_T1   = OFF_K;        // f32 384x3840 (early, dead before Kbuf)
static constexpr size_t OFF_T2   = OFF_K + 5898240;      // f32 384x768
static constexpr size_t OFF_SXB1 = OFF_K + 7077888;      // bf16 384x384
static constexpr size_t OFF_SXB2 = OFF_K + 7372800;      // bf16 384x384 (ends 7667712)
static constexpr size_t OFF_VT   = 38535168;     // bf16 (32*12*256)x784
static constexpr size_t OFF_QN   = 192675840;    // bf16 6272x768
static constexpr size_t OFF_O    = 202309632;    // bf16 6272x3072 (x_bf16 early)
static constexpr size_t OFF_XB   = OFF_O;
static constexpr size_t OFF_PS1  = 240844800;    // f32 14x384x384 (dead after reduce)
static constexpr size_t OFF_WQKVT= 240844800;    // bf16 3840x384 (over PS1)
static constexpr size_t OFF_WQT  = 243793920;    // bf16 768x384
static constexpr size_t OFF_WOUTT= 244383744;    // bf16 512x3072
static constexpr size_t OFF_PCS1 = 249102336;
static constexpr size_t OFF_PS2  = 249123840;
static constexpr size_t OFF_PCS2 = 253252608;
static constexpr size_t OFF_SX1  = 253263360;
static constexpr size_t OFF_CS1  = 253853184;
static constexpr size_t OFF_SX2  = 253854720;
static constexpr size_t OFF_CS2  = 254444544;
static constexpr size_t OFF_A1   = 254446080;
static constexpr size_t OFF_B1   = 254461440;
static constexpr size_t OFF_A2   = 254476800;
static constexpr size_t OFF_B2   = 254479872;
static constexpr size_t WS_TOTAL = 254482944;

typedef __attribute__((ext_vector_type(8))) short bf16x8;
typedef __attribute__((ext_vector_type(4))) float f32x4;

static __device__ __forceinline__ f32x4 mfma16(bf16x8 a, bf16x8 b, f32x4 c) {
  return __builtin_amdgcn_mfma_f32_16x16x32_bf16(a, b, c, 0, 0, 0);
}

__device__ __forceinline__ void gload_lds16(const void* g, void* l) {
  __builtin_amdgcn_global_load_lds(
      (const __attribute__((address_space(1))) unsigned int*)g,
      (__attribute__((address_space(3))) unsigned int*)l, 16, 0, 0);
}

__device__ __forceinline__ float hswish(float x) {
  float t = fminf(fmaxf(x + 3.0f, 0.0f), 6.0f);
  return x * t * (1.0f / 6.0f);
}

__device__ __forceinline__ void fma4x4(float (&c)[4][4], const float4 a, const float4 b) {
  c[0][0] += a.x*b.x; c[0][1] += a.x*b.y; c[0][2] += a.x*b.z; c[0][3] += a.x*b.w;
  c[1][0] += a.y*b.x; c[1][1] += a.y*b.y; c[1][2] += a.y*b.z; c[1][3] += a.y*b.w;
  c[2][0] += a.z*b.x; c[2][1] += a.z*b.y; c[2][2] += a.z*b.z; c[2][3] += a.z*b.w;
  c[3][0] += a.w*b.x; c[3][1] += a.w*b.y; c[3][2] += a.w*b.z; c[3][3] += a.w*b.w;
}

// --------------------------- X^T X partials (f32) --------------------------
template<int GATHER>
__global__ __launch_bounds__(256) void xtx_partial(
    const float* __restrict__ X, float* __restrict__ pS, float* __restrict__ pcs,
    int rows_per_chunk) {
  const int ti = blockIdx.x / 6, tj = blockIdx.x % 6;
  const int chunk = blockIdx.y;
  const int tid = threadIdx.x;
  const int tx = tid & 15, ty = tid >> 4;
  __shared__ __align__(16) float xa[32][64];
  __shared__ __align__(16) float xb[32][64];
  __shared__ float redcs[256];
  float acc[4][4] = {};
  float cs = 0.f;
  const int cq = tid & 63, rq = tid >> 6;

  for (int rr = 0; rr < rows_per_chunk; rr += 32) {
    #pragma unroll
    for (int l = 0; l < 2; ++l) {
      int f = tid + l * 256;
      int r = f >> 4, c4 = f & 15;
      int m = chunk * rows_per_chunk + rr + r;
      long grow;
      if constexpr (GATHER) {
        int bb = m / 196, t = m - bb * 196;
        int h2 = t / 14, w2 = t - h2 * 14;
        grow = (long)(bb * 784 + h2 * 56 + w2 * 2);
      } else {
        grow = m;
      }
      const float* src = X + grow * 384;
      *(float4*)&xa[r][c4 * 4] = *(const float4*)(src + ti * 64 + c4 * 4);
      *(float4*)&xb[r][c4 * 4] = *(const float4*)(src + tj * 64 + c4 * 4);
    }
    __syncthreads();
    if (ti == 0) {
      #pragma unroll
      for (int r = 0; r < 8; ++r) cs += xb[rq * 8 + r][cq];
    }
    #pragma unroll
    for (int r = 0; r < 32; ++r) {
      float4 av = *(const float4*)&xa[r][ty * 4];
      float4 bv = *(const float4*)&xb[r][tx * 4];
      fma4x4(acc, av, bv);
    }
    __syncthreads();
  }
  #pragma unroll
  for (int r = 0; r < 4; ++r) {
    *(float4*)(pS + ((long)chunk * 384 + ti * 64 + ty * 4 + r) * 384 + tj * 64 + tx * 4) =
        make_float4(acc[r][0], acc[r][1], acc[r][2], acc[r][3]);
  }
  if (ti == 0) {
    redcs[tid] = cs;
    __syncthreads();
    if (tid < 64) {
      pcs[(long)chunk * 384 + tj * 64 + tid] =
          redcs[tid] + redcs[tid + 64] + redcs[tid + 128] + redcs[tid + 192];
    }
  }
}

__global__ __launch_bounds__(256) void reduce_chunks(
    const float* __restrict__ src, float* __restrict__ dst, int nelem, int nchunks) {
  int i = blockIdx.x * 256 + threadIdx.x;
  if (i >= nelem) return;
  float s = 0.f;
  for (int c = 0; c < nchunks; ++c) s += src[(long)c * nelem + i];
  dst[i] = s;
}

// --------------------------- BN finalize -----------------------------------
// yy_j = sum_k W[k][j]*T[k][j]; mu_j = sum_k cs[k]*W[k][j]; a,b per column.
// grid = N/64, block 256 = 64 cols x 4 row-chunks of 96.
__global__ __launch_bounds__(256) void bnfinal(
    const float* __restrict__ W, const float* __restrict__ T, const float* __restrict__ cs,
    const float* __restrict__ scale, float* __restrict__ a, float* __restrict__ b,
    int N, float invM) {
  const int j = blockIdx.x * 64 + (threadIdx.x & 63);
  const int rq = threadIdx.x >> 6;
  float yy = 0.f, mu = 0.f;
  for (int k = rq * 96; k < rq * 96 + 96; ++k) {
    float w = W[(long)k * N + j];
    yy += w * T[(long)k * N + j];
    mu += cs[k] * w;
  }
  __shared__ float r1[256], r2[256];
  r1[threadIdx.x] = yy; r2[threadIdx.x] = mu;
  __syncthreads();
  if (threadIdx.x < 64) {
    int t = threadIdx.x;
    yy = r1[t] + r1[t + 64] + r1[t + 128] + r1[t + 192];
    mu = r2[t] + r2[t + 64] + r2[t + 128] + r2[t + 192];
    float mean = mu * invM;
    float var = yy * invM - mean * mean;
    float ai = rsqrtf(var + 1e-5f) * scale[j];
    a[j] = ai;
    b[j] = -mean * ai;
  }
}

// --------------------------- prep: convert / transpose ---------------------
__global__ __launch_bounds__(256) void convert_bf16(
    const float* __restrict__ in, unsigned short* __restrict__ out, long n8) {
  long i = (long)blockIdx.x * 256 + threadIdx.x;
  if (i >= n8) return;
  float4 a = ((const float4*)in)[i * 2];
  float4 b = ((const float4*)in)[i * 2 + 1];
  union { uint4 u; __hip_bfloat16 h[8]; } pk;
  pk.h[0] = __float2bfloat16(a.x); pk.h[1] = __float2bfloat16(a.y);
  pk.h[2] = __float2bfloat16(a.z); pk.h[3] = __float2bfloat16(a.w);
  pk.h[4] = __float2bfloat16(b.x); pk.h[5] = __float2bfloat16(b.y);
  pk.h[6] = __float2bfloat16(b.z); pk.h[7] = __float2bfloat16(b.w);
  ((uint4*)out)[i] = pk.u;
}

__global__ __launch_bounds__(256) void transpose_bf16(
    const float* __restrict__ in, unsigned short* __restrict__ out, int R, int C) {
  __shared__ float t[32][33];
  const int c0 = blockIdx.x * 32, r0 = blockIdx.y * 32;
  const int x = threadIdx.x & 31, y = threadIdx.x >> 5;
  #pragma unroll
  for (int i = y; i < 32; i += 8) t[i][x] = in[(long)(r0 + i) * C + c0 + x];
  __syncthreads();
  #pragma unroll
  for (int i = y; i < 32; i += 8) {
    __hip_bfloat16 v = __float2bfloat16(t[x][i]);
    out[(long)(c0 + i) * R + r0 + x] = *(unsigned short*)&v;
  }
}

// ---------------------------------------------------------------------------
// bf16 MFMA GEMM: C = A[M,K] @ Bt[N,K]^T.
// AMODE: 0 plain rows, 1 gather ::2,::2 rows.
// EPI: 0 f32 row store; 1 BN->bf16 row store; 2 BN->bf16 transposed store
//      into Vt[b][h][dv][784].
// ---------------------------------------------------------------------------
template<int AMODE, int EPI>
__global__ __launch_bounds__(256) void gemm_mfma(
    const unsigned short* __restrict__ A, const unsigned short* __restrict__ Bt,
    void* __restrict__ Cout, const float* __restrict__ ea, const float* __restrict__ eb,
    int N, int K) {
  __shared__ __align__(16) char As[16384];
  __shared__ __align__(16) char Bs[16384];
  const int tid = threadIdx.x;
  const int lane = tid & 63;
  const int wv = tid >> 6;
  const int wm = (wv >> 1) * 64, wn = (wv & 1) * 64;
  const int m0 = blockIdx.y * 128, n0 = blockIdx.x * 128;
  const int cl = lane & 15, kg = lane >> 4;

  const int srow = tid >> 3;
  const int scolb = (tid & 7) * 16;
  const int swz = scolb ^ ((srow & 7) << 4);
  const int ldsb = wv * 1024;

  long arow[4], brow[4];
  #pragma unroll
  for (int is = 0; is < 4; ++is) {
    int gm = m0 + is * 32 + srow;
    long grow;
    if constexpr (AMODE == 1) {
      int bb = gm / 196, t = gm - bb * 196;
      int h2 = t / 14, w2 = t - h2 * 14;
      grow = (long)(bb * 784 + h2 * 56 + w2 * 2);
    } else {
      grow = gm;
    }
    arow[is] = grow * (long)K;
    brow[is] = (long)(n0 + is * 32 + srow) * (long)K;
  }

  f32x4 acc[4][4];
  const f32x4 zf = {0.f, 0.f, 0.f, 0.f};
  #pragma unroll
  for (int i = 0; i < 4; ++i)
    #pragma unroll
    for (int j = 0; j < 4; ++j) acc[i][j] = zf;

  for (int k0 = 0; k0 < K; k0 += 64) {
    #pragma unroll
    for (int is = 0; is < 4; ++is) {
      gload_lds16((const char*)A  + (arow[is] + k0) * 2 + swz, As + is * 4096 + ldsb);
      gload_lds16((const char*)Bt + (brow[is] + k0) * 2 + swz, Bs + is * 4096 + ldsb);
    }
    __syncthreads();
    bf16x8 afr[4][2], bfr[4][2];
    #pragma unroll
    for (int t = 0; t < 4; ++t) {
      const int ar = wm + t * 16 + cl;
      const int br = wn + t * 16 + cl;
      const int sa = (ar & 7) << 4, sb = (br & 7) << 4;
      afr[t][0] = *(const bf16x8*)(As + ar * 128 + ((kg * 16) ^ sa));
      afr[t][1] = *(const bf16x8*)(As + ar * 128 + ((64 + kg * 16) ^ sa));
      bfr[t][0] = *(const bf16x8*)(Bs + br * 128 + ((kg * 16) ^ sb));
      bfr[t][1] = *(const bf16x8*)(Bs + br * 128 + ((64 + kg * 16) ^ sb));
    }
    #pragma unroll
    for (int mt = 0; mt < 4; ++mt)
      #pragma unroll
      for (int nt = 0; nt < 4; ++nt) {
        if constexpr (EPI == 2) {
          acc[mt][nt] = mfma16(afr[mt][0], bfr[nt][0], acc[mt][nt]);
          acc[mt][nt] = mfma16(afr[mt][1], bfr[nt][1], acc[mt][nt]);
        } else {
          acc[mt][nt] = mfma16(bfr[nt][0], afr[mt][0], acc[mt][nt]);
          acc[mt][nt] = mfma16(bfr[nt][1], afr[mt][1], acc[mt][nt]);
        }
      }
    __syncthreads();
  }

  #pragma unroll
  for (int mt = 0; mt < 4; ++mt) {
    #pragma unroll
    for (int nt = 0; nt < 4; ++nt) {
      if constexpr (EPI == 2) {
        const int gm0 = m0 + wm + mt * 16 + kg * 4;
        const int gn = n0 + wn + nt * 16 + cl;
        const int bb = gm0 / 784, kk = gm0 - bb * 784;
        const int hh = gn >> 8, dvl = gn & 255;
        const float av = ea[gn], bv = eb[gn];
        union { ushort4 u; __hip_bfloat16 h[4]; } pk;
        pk.h[0] = __float2bfloat16(acc[mt][nt][0] * av + bv);
        pk.h[1] = __float2bfloat16(acc[mt][nt][1] * av + bv);
        pk.h[2] = __float2bfloat16(acc[mt][nt][2] * av + bv);
        pk.h[3] = __float2bfloat16(acc[mt][nt][3] * av + bv);
        *(ushort4*)((unsigned short*)Cout +
                    ((long)(bb * 12 + hh) * 256 + dvl) * 784 + kk) = pk.u;
      } else {
        const int gm = m0 + wm + mt * 16 + cl;
        const int gn = n0 + wn + nt * 16 + kg * 4;
        if constexpr (EPI == 1) {
          float4 a4 = *(const float4*)(ea + gn);
          float4 b4 = *(const float4*)(eb + gn);
          union { ushort4 u; __hip_bfloat16 h[4]; } pk;
          pk.h[0] = __float2bfloat16(acc[mt][nt][0] * a4.x + b4.x);
          pk.h[1] = __float2bfloat16(acc[mt][nt][1] * a4.y + b4.y);
          pk.h[2] = __float2bfloat16(acc[mt][nt][2] * a4.z + b4.z);
          pk.h[3] = __float2bfloat16(acc[mt][nt][3] * a4.w + b4.w);
          *(ushort4*)((unsigned short*)Cout + (long)gm * N + gn) = pk.u;
        } else {
          *(float4*)((float*)Cout + (long)gm * N + gn) =
              make_float4(acc[mt][nt][0], acc[mt][nt][1], acc[mt][nt][2], acc[mt][nt][3]);
        }
      }
    }
  }
}

// ---------------------------------------------------------------------------
// Single-pass MFMA flash attention (no max; scores bounded).
// ---------------------------------------------------------------------------
__global__ __launch_bounds__(512, 4) void attn_mfma(
    const unsigned short* __restrict__ kbuf, const unsigned short* __restrict__ vt,
    const unsigned short* __restrict__ qn, const float* __restrict__ bias,
    unsigned short* __restrict__ O) {
  const int qt = blockIdx.x, h = blockIdx.y, b = blockIdx.z;
  const int tid = threadIdx.x;
  const int w = tid >> 6;
  const int lane = tid & 63;
  const int cl = lane & 15;
  const int kg = lane >> 4;
  const int qbase = qt * 112;
  const int valid = 196 - qbase > 112 ? 112 : 196 - qbase;
  const int bh = b * 12 + h;

  __shared__ __align__(16) short Qs[112][72];
  __shared__ __align__(16) short Ks[2][64][72];
  __shared__ __align__(16) short pPs[112][72];
  __shared__ float pred[4][112];
  __shared__ float lsum[112];

  const bf16x8 zero8 = {0,0,0,0,0,0,0,0};
  const f32x4 zerof = {0.f,0.f,0.f,0.f};

  for (int f = tid; f < 896; f += 512) {
    int row = f >> 3, d8 = f & 7;
    bf16x8 v = zero8;
    if (row < valid)
      v = *(const bf16x8*)(qn + (long)(b * 196 + qbase + row) * 768 + h * 64 + d8 * 8);
    *(bf16x8*)&Qs[row][d8 * 8] = v;
  }
  {
    int kk = tid >> 3, d8 = tid & 7;
    bf16x8 v = *(const bf16x8*)(kbuf + ((long)b * 784 + kk) * 768 + h * 64 + d8 * 8);
    *(bf16x8*)&Ks[0][kk][d8 * 8] = v;
  }
  __syncthreads();

  const int mt0 = w >> 2, snt = w & 3;
  const int kb = kg * 8;

  f32x4 acc[7][2];
  #pragma unroll
  for (int mt = 0; mt < 7; ++mt) { acc[mt][0] = zerof; acc[mt][1] = zerof; }
  float lpart[4] = {0.f, 0.f, 0.f, 0.f};

  for (int kt = 0; kt < 13; ++kt) {
    const int k0 = kt * 64;
    const int cur = kt & 1;
    if (kt < 12) {
      int kk = tid >> 3, d8 = tid & 7;
      bf16x8 v = zero8;
      if (k0 + 64 + kk < 784)
        v = *(const bf16x8*)(kbuf + ((long)b * 784 + k0 + 64 + kk) * 768 + h * 64 + d8 * 8);
      *(bf16x8*)&Ks[cur ^ 1][kk][d8 * 8] = v;
    }
    bf16x8 vf00, vf01, vf10, vf11;
    {
      const long vrow0 = ((long)bh * 256 + w * 32 + cl) * 784;
      const long vrow1 = ((long)bh * 256 + w * 32 + 16 + cl) * 784;
      vf00 = *(const bf16x8*)(vt + vrow0 + k0 + kb);
      vf10 = *(const bf16x8*)(vt + vrow0 + k0 + 32 + kb);
      vf01 = *(const bf16x8*)(vt + vrow1 + k0 + kb);
      vf11 = *(const bf16x8*)(vt + vrow1 + k0 + 32 + kb);
    }
    #pragma unroll
    for (int i = 0; i < 4; ++i) {
      int mt = mt0 + 2 * i;
      if (mt >= 7) break;
      bf16x8 q0 = *(const bf16x8*)&Qs[mt * 16 + cl][kb];
      bf16x8 q1 = *(const bf16x8*)&Qs[mt * 16 + cl][32 + kb];
      bf16x8 kk0 = *(const bf16x8*)&Ks[cur][snt * 16 + cl][kb];
      bf16x8 kk1 = *(const bf16x8*)&Ks[cur][snt * 16 + cl][32 + kb];
      f32x4 s = mfma16(kk1, q1, mfma16(kk0, q0, zerof));
      const int rowl = mt * 16 + cl;
      const int key0 = k0 + snt * 16 + kg * 4;
      const bool ok = (rowl < valid) && (key0 < 784);
      float4 b4 = make_float4(0.f, 0.f, 0.f, 0.f);
      if (ok) b4 = *(const float4*)(bias + (long)(qbase + rowl) * 784 + key0);
      float p0 = ok ? __expf(s[0] * 0.125f + b4.x) : 0.f;
      float p1 = ok ? __expf(s[1] * 0.125f + b4.y) : 0.f;
      float p2 = ok ? __expf(s[2] * 0.125f + b4.z) : 0.f;
      float p3 = ok ? __expf(s[3] * 0.125f + b4.w) : 0.f;
      lpart[i] += (p0 + p1) + (p2 + p3);
      union { ushort4 u; __hip_bfloat16 hh[4]; } pk;
      pk.hh[0] = __float2bfloat16(p0);
      pk.hh[1] = __float2bfloat16(p1);
      pk.hh[2] = __float2bfloat16(p2);
      pk.hh[3] = __float2bfloat16(p3);
      *(ushort4*)&pPs[rowl][snt * 16 + kg * 4] = pk.u;
    }
    __syncthreads();
    #pragma unroll
    for (int mt = 0; mt < 7; ++mt) {
      bf16x8 pa0 = *(const bf16x8*)&pPs[mt * 16 + cl][kb];
      bf16x8 pa1 = *(const bf16x8*)&pPs[mt * 16 + cl][32 + kb];
      acc[mt][0] = mfma16(pa0, vf00, acc[mt][0]);
      acc[mt][0] = mfma16(pa1, vf10, acc[mt][0]);
      acc[mt][1] = mfma16(pa0, vf01, acc[mt][1]);
      acc[mt][1] = mfma16(pa1, vf11, acc[mt][1]);
    }
    __syncthreads();
  }

  #pragma unroll
  for (int i = 0; i < 4; ++i) {
    int mt = mt0 + 2 * i;
    if (mt >= 7) break;
    float v = lpart[i];
    v += __shfl_xor(v, 16);
    v += __shfl_xor(v, 32);
    if (kg == 0) pred[snt][mt * 16 + cl] = v;
  }
  __syncthreads();
  if (tid < 112)
    lsum[tid] = (pred[0][tid] + pred[1][tid]) + (pred[2][tid] + pred[3][tid]);
  __syncthreads();

  #pragma unroll
  for (int mt = 0; mt < 7; ++mt) {
    #pragma unroll
    for (int r = 0; r < 4; ++r) {
      const int rl = mt * 16 + kg * 4 + r;
      if (rl < valid) {
        const float inv = 1.0f / lsum[rl];
        #pragma unroll
        for (int nt2 = 0; nt2 < 2; ++nt2) {
          float ov = hswish(acc[mt][nt2][r] * inv);
          __hip_bfloat16 hv = __float2bfloat16(ov);
          O[(long)(b * 196 + qbase + rl) * 3072 + h * 256 + w * 32 + nt2 * 16 + cl] =
              *(unsigned short*)&hv;
        }
      }
    }
  }
}

// ---------------------------------------------------------------------------
extern "C" void kernel_launch(void* const* d_in, const int* in_sizes, int n_in,
                              void* d_out, int out_size, void* d_ws, size_t ws_size,
                              hipStream_t stream) {
  if (ws_size < WS_TOTAL) return;

  const float* x    = (const float*)d_in[0];
  const float* Wqkv = (const float*)d_in[1];
  const float* bn1s = (const float*)d_in[2];
  const float* Wq   = (const float*)d_in[3];
  const float* bn2s = (const float*)d_in[4];
  const float* bias = (const float*)d_in[5];
  const float* Wout = (const float*)d_in[6];

  char* ws = (char*)d_ws;
  unsigned short* kb   = (unsigned short*)(ws + OFF_K);
  unsigned short* vtb  = (unsigned short*)(ws + OFF_VT);
  unsigned short* qnb  = (unsigned short*)(ws + OFF_QN);
  unsigned short* xb   = (unsigned short*)(ws + OFF_XB);
  unsigned short* Ob   = (unsigned short*)(ws + OFF_O);
  unsigned short* wqkvt= (unsigned short*)(ws + OFF_WQKVT);
  unsigned short* wqt  = (unsigned short*)(ws + OFF_WQT);
  unsigned short* woutt= (unsigned short*)(ws + OFF_WOUTT);
  float* t1   = (float*)(ws + OFF_T1);
  float* t2   = (float*)(ws + OFF_T2);
  unsigned short* sxb1 = (unsigned short*)(ws + OFF_SXB1);
  unsigned short* sxb2 = (unsigned short*)(ws + OFF_SXB2);
  float* ps1  = (float*)(ws + OFF_PS1);
  float* pcs1 = (float*)(ws + OFF_PCS1);
  float* ps2  = (float*)(ws + OFF_PS2);
  float* pcs2 = (float*)(ws + OFF_PCS2);
  float* sx1  = (float*)(ws + OFF_SX1);
  float* cs1  = (float*)(ws + OFF_CS1);
  float* sx2  = (float*)(ws + OFF_SX2);
  float* cs2  = (float*)(ws + OFF_CS2);
  float* a1w  = (float*)(ws + OFF_A1);
  float* b1w  = (float*)(ws + OFF_B1);
  float* a2w  = (float*)(ws + OFF_A2);
  float* b2w  = (float*)(ws + OFF_B2);
  float* out  = (float*)d_out;

  // stats
  xtx_partial<0><<<dim3(36, CH1), 256, 0, stream>>>(x, ps1, pcs1, M1 / CH1);
  xtx_partial<1><<<dim3(36, CH2), 256, 0, stream>>>(x, ps2, pcs2, M2 / CH2);
  reduce_chunks<<<dim3(576), 256, 0, stream>>>(ps1, sx1, 384 * 384, CH1);
  reduce_chunks<<<dim3(2),   256, 0, stream>>>(pcs1, cs1, 384, CH1);
  reduce_chunks<<<dim3(576), 256, 0, stream>>>(ps2, sx2, 384 * 384, CH2);
  reduce_chunks<<<dim3(2),   256, 0, stream>>>(pcs2, cs2, 384, CH2);

  // bf16 operand prep (PS1 dead after reduces; transposes precede T-GEMMs)
  convert_bf16<<<dim3(4704), 256, 0, stream>>>(x, xb, (long)M1 * Kc / 8);
  transpose_bf16<<<dim3(120, 12), 256, 0, stream>>>(Wqkv, wqkvt, Kc, N1);
  transpose_bf16<<<dim3(24, 12),  256, 0, stream>>>(Wq,   wqt,   Kc, Dq);
  transpose_bf16<<<dim3(16, 96),  256, 0, stream>>>(Wout, woutt, 4 * Dq, OUTD);
  convert_bf16<<<dim3(72), 256, 0, stream>>>(sx1, sxb1, 384 * 384 / 8);
  convert_bf16<<<dim3(72), 256, 0, stream>>>(sx2, sxb2, 384 * 384 / 8);

  // BN coefficients: T = Sx @ W via MFMA, then column reduce
  gemm_mfma<0, 0><<<dim3(30, 3), 256, 0, stream>>>(sxb1, wqkvt, t1, nullptr, nullptr, N1, Kc);
  gemm_mfma<0, 0><<<dim3(6, 3),  256, 0, stream>>>(sxb2, wqt,   t2, nullptr, nullptr, Dq, Kc);
  bnfinal<<<dim3(60), 256, 0, stream>>>(Wqkv, t1, cs1, bn1s, a1w, b1w, N1, 1.f / (float)M1);
  bnfinal<<<dim3(12), 256, 0, stream>>>(Wq,   t2, cs2, bn2s, a2w, b2w, Dq, 1.f / (float)M2);

  // projections
  gemm_mfma<0, 1><<<dim3(6, 196), 256, 0, stream>>>(xb, wqkvt, kb, a1w, b1w, 768, Kc);
  gemm_mfma<0, 2><<<dim3(24, 196), 256, 0, stream>>>(
      xb, wqkvt + (long)768 * Kc, vtb, a1w + 768, b1w + 768, 3072, Kc);
  gemm_mfma<1, 1><<<dim3(6, 49), 256, 0, stream>>>(xb, wqt, qnb, a2w, b2w, Dq, Kc);

  // attention -> hswish(O)
  attn_mfma<<<dim3(2, 12, 32), 512, 0, stream>>>(kb, vtb, qnb, bias, Ob);

  // out
  gemm_mfma<0, 0><<<dim3(4, 49), 256, 0, stream>>>(Ob, woutt, out, nullptr, nullptr, OUTD, 4 * Dq);
}